// Round 1
// baseline (175120.447 us; speedup 1.0000x reference)
//
#include <hip/hip_runtime.h>

#define BB 32
#define TT 256
#define SS 1600
#define DE 1024
#define VV 1000
#define EM 512
#define PR 256
#define LU 1024
#define AA 128
#define FF 32
#define KK 31

// ---------------- once-per-call precompute ----------------

// keys[b,s,a] = sum_k memory[b,s,k] * Wmem[k,a]
__global__ __launch_bounds__(256) void keys_kernel(const float* __restrict__ mem,
                                                   const float* __restrict__ Wmem,
                                                   float* __restrict__ keys)
{
  int stile = blockIdx.x;           // 200 tiles of 8 s-rows
  int b = blockIdx.y;
  int t = threadIdx.x;
  __shared__ float Xt[8 * 1032];    // padded stride to avoid bank conflicts
  const float* mp = mem + ((size_t)b * SS + (size_t)stile * 8) * DE;
  for (int li = t; li < 8 * 256; li += 256) {
    int row = li >> 8, c4 = li & 255;
    float4 v = *(const float4*)(mp + row * DE + c4 * 4);
    *(float4*)(Xt + row * 1032 + c4 * 4) = v;
  }
  __syncthreads();
  int sl = t >> 5, u = t & 31;
  float acc[4] = {0.f, 0.f, 0.f, 0.f};
  for (int k = 0; k < DE; k++) {
    float x = Xt[sl * 1032 + k];
    const float* wr = Wmem + k * AA;
#pragma unroll
    for (int jj = 0; jj < 4; jj++) acc[jj] += x * wr[u + 32 * jj];
  }
  float* kp = keys + ((size_t)b * SS + (size_t)stile * 8 + sl) * AA;
#pragma unroll
  for (int jj = 0; jj < 4; jj++) kp[u + 32 * jj] = acc[jj];
}

// M[k,a] = sum_c conv_k[k,0,c] * Wloc[c,a]  (collapses conv + ploc matmul)
__global__ void mconv_kernel(const float* __restrict__ ck, const float* __restrict__ Wloc,
                             float* __restrict__ M)
{
  int a = threadIdx.x;  // 128
  int k = blockIdx.x;   // 31
  float acc = 0.f;
  for (int c = 0; c < FF; c++) acc += ck[k * FF + c] * Wloc[c * AA + a];
  M[k * AA + a] = acc;
}

// Prenet for ALL timesteps (depends only on tokens). P layout: [t][b][PR]
__global__ __launch_bounds__(256) void prenet_all(const int* __restrict__ tokens,
    const float* __restrict__ emb, const float* __restrict__ Wp1, const float* __restrict__ bp1,
    const float* __restrict__ Wp2, const float* __restrict__ bp2, float* __restrict__ P)
{
  int tstep = blockIdx.x;
  int bh = blockIdx.y;  // batch half: 16 rows
  int t = threadIdx.x;
  __shared__ float X[16 * 512];
  __shared__ float P1[16 * 256];
  for (int li = t; li < 16 * 128; li += 256) {
    int bb = li >> 7, c4 = li & 127;
    int tok = tokens[(bh * 16 + bb) * TT + tstep];
    *(float4*)(X + bb * 512 + c4 * 4) = *(const float4*)(emb + (size_t)tok * EM + c4 * 4);
  }
  __syncthreads();
  int j = t;
  float acc[16];
#pragma unroll
  for (int i = 0; i < 16; i++) acc[i] = 0.f;
  for (int k = 0; k < EM; k++) {
    float w = Wp1[k * PR + j];
#pragma unroll
    for (int i = 0; i < 16; i++) acc[i] += X[i * 512 + k] * w;
  }
#pragma unroll
  for (int i = 0; i < 16; i++) P1[i * 256 + j] = fmaxf(acc[i] + bp1[j], 0.f);
  __syncthreads();
#pragma unroll
  for (int i = 0; i < 16; i++) acc[i] = 0.f;
  for (int k = 0; k < PR; k++) {
    float w = Wp2[k * PR + j];
#pragma unroll
    for (int i = 0; i < 16; i++) acc[i] += P1[i * 256 + k] * w;
  }
  float* outp = P + (size_t)tstep * BB * PR + (size_t)bh * 16 * PR;
#pragma unroll
  for (int i = 0; i < 16; i++) outp[i * PR + j] = fmaxf(acc[i] + bp2[j], 0.f);
}

// ---------------- per-step kernels ----------------

// Batched GEMV partial: zpart[kc][b][j] = sum_{k in chunk} xcat[b][k] * W[k][j]
// xcat = concat of up to 3 segments. Thread tile: 8 batch x 4 cols.
// Weights: coalesced float4; x: wave-uniform global loads (L1 broadcast), no LDS.
__global__ __launch_bounds__(256) void gemv_part(
    const float* __restrict__ x0, const float* __restrict__ W0r, int len0,
    const float* __restrict__ x1, const float* __restrict__ W1r, int len1,
    const float* __restrict__ x2, const float* __restrict__ W2r, int len2,
    int N, float* __restrict__ zpart)
{
  int jb = blockIdx.x, kc = blockIdx.y, KS = gridDim.y;
  int t = threadIdx.x;
  int jq = t & 63, bq = t >> 6;
  int j = jb * 256 + jq * 4;
  int K = len0 + len1 + len2;
  int chunk = (K + KS - 1) / KS;
  int k0 = kc * chunk, k1 = min(K, k0 + chunk);
  float acc[8][4];
#pragma unroll
  for (int bi = 0; bi < 8; bi++) {
    acc[bi][0] = 0.f; acc[bi][1] = 0.f; acc[bi][2] = 0.f; acc[bi][3] = 0.f;
  }
  if (j < N) {
    for (int k = k0; k < k1; k++) {
      const float* xs; const float* Wr; int ks; int xstr;
      if (k < len0)                 { xs = x0; Wr = W0r; ks = k;               xstr = len0; }
      else if (k < len0 + len1)     { xs = x1; Wr = W1r; ks = k - len0;        xstr = len1; }
      else                          { xs = x2; Wr = W2r; ks = k - len0 - len1; xstr = len2; }
      float4 w = *(const float4*)(Wr + (size_t)ks * N + j);
#pragma unroll
      for (int bi = 0; bi < 8; bi++) {
        float xv = xs[(size_t)(bq * 8 + bi) * xstr + ks];
        acc[bi][0] += xv * w.x; acc[bi][1] += xv * w.y;
        acc[bi][2] += xv * w.z; acc[bi][3] += xv * w.w;
      }
    }
#pragma unroll
    for (int bi = 0; bi < 8; bi++) {
      int b = bq * 8 + bi;
      *(float4*)(zpart + ((size_t)kc * BB + b) * N + j) =
          make_float4(acc[bi][0], acc[bi][1], acc[bi][2], acc[bi][3]);
    }
  }
}

// Reduce KS partials, apply gates i,f,g,o, update h,c in place.
__global__ __launch_bounds__(256) void lstm_finish(const float* __restrict__ zpart, int KS,
    const float* __restrict__ bias, float* __restrict__ h, float* __restrict__ c)
{
  int b = blockIdx.x;
  int j = blockIdx.y * 256 + threadIdx.x;  // [0,1024)
  float zi = bias[j], zf = bias[LU + j], zg = bias[2 * LU + j], zo = bias[3 * LU + j];
  for (int kc = 0; kc < KS; kc++) {
    const float* zpt = zpart + ((size_t)kc * BB + b) * 4096;
    zi += zpt[j]; zf += zpt[LU + j]; zg += zpt[2 * LU + j]; zo += zpt[3 * LU + j];
  }
  float si = 1.f / (1.f + expf(-zi));
  float sf = 1.f / (1.f + expf(-zf));
  float tg = tanhf(zg);
  float so = 1.f / (1.f + expf(-zo));
  float cn = sf * c[b * LU + j] + si * tg;
  float hn = so * tanhf(cn);
  c[b * LU + j] = cn;
  h[b * LU + j] = hn;
}

__global__ __launch_bounds__(128) void pq_kernel(const float* __restrict__ h_a,
    const float* __restrict__ Wq, float* __restrict__ pq)
{
  int b = blockIdx.x, a = threadIdx.x;
  float acc = 0.f;
  const float* hp = h_a + b * LU;
  for (int k = 0; k < LU; k++) acc += hp[k] * Wq[k * AA + a];
  pq[b * AA + a] = acc;
}

// e[b,s] = (s<len) ? sum_a tanh(keys+pq+ploc)*Wv[a] + bv : -1e9
// ploc via direct 31-tap conv with precomputed M
__global__ __launch_bounds__(256) void energy_kernel(const float* __restrict__ keys,
    const float* __restrict__ pq, const float* __restrict__ M, const float* __restrict__ ast,
    const float* __restrict__ Wv, const float* __restrict__ bv, const int* __restrict__ mlen,
    float* __restrict__ e)
{
  int stile = blockIdx.x, b = blockIdx.y;
  int t = threadIdx.x;
  int s0 = stile * 16;
  __shared__ float astw[48];
  __shared__ float Ml[KK * AA];
  __shared__ float wvl[AA];
  __shared__ float pql[AA];
  if (t < 46) { int s = s0 + t - 15; astw[t] = (s >= 0 && s < SS) ? ast[b * SS + s] : 0.f; }
  if (t >= 64 && t < 192) { int a = t - 64; wvl[a] = Wv[a]; pql[a] = pq[b * AA + a]; }
  for (int i = t; i < KK * AA; i += 256) Ml[i] = M[i];
  __syncthreads();
  int sl = t >> 4, u = t & 15;    // 16 s-rows x 16 lanes; a = u + 16*jj (bank-conflict-free)
  int s = s0 + sl;
  const float* kp = keys + ((size_t)b * SS + s) * AA;
  float arg[8];
#pragma unroll
  for (int jj = 0; jj < 8; jj++) { int a = u + 16 * jj; arg[jj] = kp[a] + pql[a]; }
#pragma unroll
  for (int k = 0; k < KK; k++) {
    float aw = astw[sl + k];
#pragma unroll
    for (int jj = 0; jj < 8; jj++) arg[jj] += aw * Ml[k * AA + u + 16 * jj];
  }
  float v = 0.f;
#pragma unroll
  for (int jj = 0; jj < 8; jj++) v += tanhf(arg[jj]) * wvl[u + 16 * jj];
#pragma unroll
  for (int m = 1; m < 16; m <<= 1) v += __shfl_xor(v, m);
  if (u == 0) e[b * SS + s] = (s < mlen[b]) ? (v + bv[0]) : -1e9f;
}

__global__ __launch_bounds__(256) void softmax_kernel(const float* __restrict__ e,
    float* __restrict__ al, float* __restrict__ ast)
{
  int b = blockIdx.x, t = threadIdx.x;
  __shared__ float red[4];
  float m = -3e38f;
  for (int s = t; s < SS; s += 256) m = fmaxf(m, e[b * SS + s]);
#pragma unroll
  for (int msk = 1; msk < 64; msk <<= 1) m = fmaxf(m, __shfl_xor(m, msk));
  if ((t & 63) == 0) red[t >> 6] = m;
  __syncthreads();
  m = fmaxf(fmaxf(red[0], red[1]), fmaxf(red[2], red[3]));
  __syncthreads();
  float sum = 0.f;
  for (int s = t; s < SS; s += 256) sum += expf(e[b * SS + s] - m);
#pragma unroll
  for (int msk = 1; msk < 64; msk <<= 1) sum += __shfl_xor(sum, msk);
  if ((t & 63) == 0) red[t >> 6] = sum;
  __syncthreads();
  float inv = 1.f / (red[0] + red[1] + red[2] + red[3]);
  for (int s = t; s < SS; s += 256) {
    float a_ = expf(e[b * SS + s] - m) * inv;
    al[b * SS + s] = a_;
    ast[b * SS + s] += a_;
  }
}

// ctx partial over s-chunks of 200 (parallelism to saturate HBM)
__global__ __launch_bounds__(256) void ctx_part(const float* __restrict__ al,
    const float* __restrict__ mem, float* __restrict__ cp)
{
  int dc = blockIdx.x, b = blockIdx.y, sc = blockIdx.z;
  int t = threadIdx.x, d = dc * 256 + t;
  __shared__ float alsh[200];
  for (int i = t; i < 200; i += 256) alsh[i] = al[b * SS + sc * 200 + i];
  __syncthreads();
  float acc = 0.f;
  const float* mp = mem + ((size_t)b * SS + (size_t)sc * 200) * DE + d;
#pragma unroll 4
  for (int i = 0; i < 200; i++) acc += alsh[i] * mp[(size_t)i * DE];
  cp[((size_t)sc * BB + b) * DE + d] = acc;
}

__global__ __launch_bounds__(256) void ctx_red(const float* __restrict__ cp,
                                               float* __restrict__ ctx)
{
  int dc = blockIdx.x, b = blockIdx.y;
  int d = dc * 256 + threadIdx.x;
  float acc = 0.f;
#pragma unroll
  for (int sc = 0; sc < 8; sc++) acc += cp[((size_t)sc * BB + b) * DE + d];
  ctx[b * DE + d] = acc;
}

__global__ __launch_bounds__(256) void cls_fin(const float* __restrict__ zpart, int KS,
    const float* __restrict__ bc, float* __restrict__ out, int tstep)
{
  int jb = blockIdx.x, b = blockIdx.y;
  int v = jb * 256 + threadIdx.x;
  if (v < VV) {
    float acc = bc[v];
    for (int kc = 0; kc < KS; kc++) acc += zpart[((size_t)kc * BB + b) * VV + v];
    out[(size_t)b * TT * VV + (size_t)tstep * VV + v] = acc;
  }
}

__global__ __launch_bounds__(256) void stp_kernel(const float* __restrict__ h1,
    const float* __restrict__ Ws, const float* __restrict__ bs,
    float* __restrict__ out, int tstep)
{
  int b = blockIdx.x, t = threadIdx.x;
  const float* cr = out + (size_t)b * TT * VV + (size_t)tstep * VV;
  float acc = 0.f;
  for (int k = t; k < LU; k += 256) acc += h1[b * LU + k] * Ws[k];
  for (int v = t; v < VV; v += 256) acc += cr[v] * Ws[LU + v];
#pragma unroll
  for (int msk = 1; msk < 64; msk <<= 1) acc += __shfl_xor(acc, msk);
  __shared__ float red[4];
  if ((t & 63) == 0) red[t >> 6] = acc;
  __syncthreads();
  if (t == 0) out[(size_t)BB * TT * VV + (size_t)b * TT + tstep] =
      red[0] + red[1] + red[2] + red[3] + bs[0];
}

// ---------------- launcher ----------------

extern "C" void kernel_launch(void* const* d_in, const int* in_sizes, int n_in,
                              void* d_out, int out_size, void* d_ws, size_t ws_size,
                              hipStream_t stream)
{
  const int*   tokens = (const int*)  d_in[0];
  const float* memory = (const float*)d_in[1];
  const int*   mlen   = (const int*)  d_in[2];
  const float* emb    = (const float*)d_in[3];
  const float* Wp1    = (const float*)d_in[4];
  const float* bp1    = (const float*)d_in[5];
  const float* Wp2    = (const float*)d_in[6];
  const float* bp2    = (const float*)d_in[7];
  const float* Wq     = (const float*)d_in[8];
  const float* Wmem   = (const float*)d_in[9];
  const float* convk  = (const float*)d_in[10];
  const float* Wloc   = (const float*)d_in[11];
  const float* Wv     = (const float*)d_in[12];
  const float* bv     = (const float*)d_in[13];
  const float* Wa     = (const float*)d_in[14];
  const float* Ua     = (const float*)d_in[15];
  const float* ba     = (const float*)d_in[16];
  const float* W0     = (const float*)d_in[17];
  const float* U0     = (const float*)d_in[18];
  const float* b0     = (const float*)d_in[19];
  const float* W1     = (const float*)d_in[20];
  const float* U1     = (const float*)d_in[21];
  const float* b1     = (const float*)d_in[22];
  const float* Wc     = (const float*)d_in[23];
  const float* bc     = (const float*)d_in[24];
  const float* Ws     = (const float*)d_in[25];
  const float* bs     = (const float*)d_in[26];
  float* out = (float*)d_out;
  float* ws = (float*)d_ws;

  size_t o = 0;
  float* keys  = ws + o;  o += (size_t)BB * SS * AA;   // 6,553,600
  float* M     = ws + o;  o += 4096;                   // 31*128 rounded
  float* P_all = ws + o;  o += (size_t)TT * BB * PR;   // 2,097,152
  float* st    = ws + o;                               // zero-init state block
  float* h_a = st;
  float* c_a = h_a + BB * LU;
  float* h0  = c_a + BB * LU;
  float* c0  = h0 + BB * LU;
  float* h1  = c0 + BB * LU;
  float* c1  = h1 + BB * LU;
  float* ctx = c1 + BB * LU;
  float* ast = ctx + BB * DE;
  size_t stcount = (size_t)6 * BB * LU + (size_t)BB * DE + (size_t)BB * SS;
  o += stcount;
  float* pq   = ws + o;  o += (size_t)BB * AA;
  float* ebuf = ws + o;  o += (size_t)BB * SS;
  float* al   = ws + o;  o += (size_t)BB * SS;
  float* zp   = ws + o;  o += (size_t)16 * BB * 4096;  // gemv partials
  float* cp   = ws + o;  o += (size_t)8 * BB * DE;     // ctx partials

  hipMemsetAsync(st, 0, stcount * sizeof(float), stream);
  keys_kernel<<<dim3(200, BB), 256, 0, stream>>>(memory, Wmem, keys);
  mconv_kernel<<<KK, AA, 0, stream>>>(convk, Wloc, M);
  prenet_all<<<dim3(TT, 2), 256, 0, stream>>>(tokens, emb, Wp1, bp1, Wp2, bp2, P_all);

  for (int tstep = 0; tstep < TT; tstep++) {
    // attention LSTM: z = [p,ctx]@Wa + h_a@Ua
    gemv_part<<<dim3(16, 16), 256, 0, stream>>>(
        P_all + (size_t)tstep * BB * PR, Wa, PR,
        ctx, Wa + (size_t)PR * 4096, DE,
        h_a, Ua, LU, 4096, zp);
    lstm_finish<<<dim3(BB, 4), 256, 0, stream>>>(zp, 16, ba, h_a, c_a);
    pq_kernel<<<BB, AA, 0, stream>>>(h_a, Wq, pq);
    energy_kernel<<<dim3(100, BB), 256, 0, stream>>>(keys, pq, M, ast, Wv, bv, mlen, ebuf);
    softmax_kernel<<<BB, 256, 0, stream>>>(ebuf, al, ast);
    ctx_part<<<dim3(4, BB, 8), 256, 0, stream>>>(al, memory, cp);
    ctx_red<<<dim3(4, BB), 256, 0, stream>>>(cp, ctx);
    // LSTM0: z = [h_a,ctx]@W0 + h0@U0
    gemv_part<<<dim3(16, 16), 256, 0, stream>>>(
        h_a, W0, LU,
        ctx, W0 + (size_t)LU * 4096, DE,
        h0, U0, LU, 4096, zp);
    lstm_finish<<<dim3(BB, 4), 256, 0, stream>>>(zp, 16, b0, h0, c0);
    // LSTM1: z = h0@W1 + h1@U1
    gemv_part<<<dim3(16, 16), 256, 0, stream>>>(
        h0, W1, LU,
        h1, U1, LU,
        h0, W1, 0, 4096, zp);
    lstm_finish<<<dim3(BB, 4), 256, 0, stream>>>(zp, 16, b1, h1, c1);
    // cls = [h1,ctx]@Wc + bc
    gemv_part<<<dim3(4, 16), 256, 0, stream>>>(
        h1, Wc, LU,
        ctx, Wc + (size_t)LU * VV, DE,
        h1, Wc, 0, VV, zp);
    cls_fin<<<dim3(4, BB), 256, 0, stream>>>(zp, 16, bc, out, tstep);
    stp_kernel<<<BB, 256, 0, stream>>>(h1, Ws, bs, out, tstep);
  }
}

// Round 2
// 50533.572 us; speedup vs baseline: 3.4654x; 3.4654x over previous
//
#include <hip/hip_runtime.h>

#define BB 32
#define TT 256
#define SS 1600
#define DE 1024
#define VV 1000
#define EM 512
#define PR 256
#define LU 1024
#define AA 128
#define FF 32
#define KK 31
#define KS 16      // k-split per gemv
#define KSTEP 16   // rows per stage
#define NBUF 3     // LDS ring buffers

__device__ __forceinline__ void gload16(const float* g, float* l) {
  __builtin_amdgcn_global_load_lds(
      (const __attribute__((address_space(1))) void*)g,
      (__attribute__((address_space(3))) void*)l, 16, 0, 0);
}

// ---------------- once-per-call precompute ----------------

__global__ __launch_bounds__(256) void keys_kernel(const float* __restrict__ mem,
                                                   const float* __restrict__ Wmem,
                                                   float* __restrict__ keys)
{
  int stile = blockIdx.x;           // 200 tiles of 8 s-rows
  int b = blockIdx.y;
  int t = threadIdx.x;
  __shared__ float Xt[8 * 1032];
  const float* mp = mem + ((size_t)b * SS + (size_t)stile * 8) * DE;
  for (int li = t; li < 8 * 256; li += 256) {
    int row = li >> 8, c4 = li & 255;
    float4 v = *(const float4*)(mp + row * DE + c4 * 4);
    *(float4*)(Xt + row * 1032 + c4 * 4) = v;
  }
  __syncthreads();
  int sl = t >> 5, u = t & 31;
  float acc[4] = {0.f, 0.f, 0.f, 0.f};
  for (int k = 0; k < DE; k++) {
    float x = Xt[sl * 1032 + k];
    const float* wr = Wmem + k * AA;
#pragma unroll
    for (int jj = 0; jj < 4; jj++) acc[jj] += x * wr[u + 32 * jj];
  }
  float* kp = keys + ((size_t)b * SS + (size_t)stile * 8 + sl) * AA;
#pragma unroll
  for (int jj = 0; jj < 4; jj++) kp[u + 32 * jj] = acc[jj];
}

__global__ void mconv_kernel(const float* __restrict__ ck, const float* __restrict__ Wloc,
                             float* __restrict__ M)
{
  int a = threadIdx.x;  // 128
  int k = blockIdx.x;   // 31
  float acc = 0.f;
  for (int c = 0; c < FF; c++) acc += ck[k * FF + c] * Wloc[c * AA + a];
  M[k * AA + a] = acc;
}

__global__ __launch_bounds__(256) void prenet_all(const int* __restrict__ tokens,
    const float* __restrict__ emb, const float* __restrict__ Wp1, const float* __restrict__ bp1,
    const float* __restrict__ Wp2, const float* __restrict__ bp2, float* __restrict__ P)
{
  int tstep = blockIdx.x;
  int bh = blockIdx.y;
  int t = threadIdx.x;
  __shared__ float X[16 * 512];
  __shared__ float P1[16 * 256];
  for (int li = t; li < 16 * 128; li += 256) {
    int bb = li >> 7, c4 = li & 127;
    int tok = tokens[(bh * 16 + bb) * TT + tstep];
    *(float4*)(X + bb * 512 + c4 * 4) = *(const float4*)(emb + (size_t)tok * EM + c4 * 4);
  }
  __syncthreads();
  int j = t;
  float acc[16];
#pragma unroll
  for (int i = 0; i < 16; i++) acc[i] = 0.f;
  for (int k = 0; k < EM; k++) {
    float w = Wp1[k * PR + j];
#pragma unroll
    for (int i = 0; i < 16; i++) acc[i] += X[i * 512 + k] * w;
  }
#pragma unroll
  for (int i = 0; i < 16; i++) P1[i * 256 + j] = fmaxf(acc[i] + bp1[j], 0.f);
  __syncthreads();
#pragma unroll
  for (int i = 0; i < 16; i++) acc[i] = 0.f;
  for (int k = 0; k < PR; k++) {
    float w = Wp2[k * PR + j];
#pragma unroll
    for (int i = 0; i < 16; i++) acc[i] += P1[i * 256 + k] * w;
  }
  float* outp = P + (size_t)tstep * BB * PR + (size_t)bh * 16 * PR;
#pragma unroll
  for (int i = 0; i < 16; i++) outp[i * PR + j] = fmaxf(acc[i] + bp2[j], 0.f);
}

// ---------------- deep-pipelined batched GEMV ----------------
// zpart[kc][b][j] = sum_{k in chunk} xcat[b][k] * W[k][j]
// Weight rows streamed HBM -> LDS via global_load_lds ring (counted vmcnt),
// x chunk staged to LDS once per block. Segment boundaries are multiples of 16.
__global__ __launch_bounds__(256) void gemv_pipe(
    const float* __restrict__ x0, int len0,
    const float* __restrict__ x1, int len1,
    const float* __restrict__ x2, int len2,
    const float* __restrict__ Wmat, const float* __restrict__ Umat,
    int N, int chunk, float* __restrict__ zp)
{
  __shared__ float wl[NBUF * KSTEP * 256];   // 48 KB
  __shared__ float xl[32 * 256];             // 32 KB
  int jb = blockIdx.x, kc = blockIdx.y;
  int t = threadIdx.x;
  int lane = t & 63;
  int wv = __builtin_amdgcn_readfirstlane(t >> 6);
  int lenW = len0 + len1;
  int k0 = kc * chunk;
  int nst = chunk >> 4;
  int colbase = jb * 256 + lane * 4;
  bool jok = (colbase + 4 <= N);

  // stage x chunk into xl[b][0..chunk)
  if (t < chunk) {
    int k = k0 + t;
    const float* xp; int str; int off;
    if (k < len0)      { xp = x0; str = len0; off = k; }
    else if (k < lenW) { xp = x1; str = len1; off = k - len0; }
    else               { xp = x2; str = len2; off = k - lenW; }
    for (int b = 0; b < 32; b++) xl[b * 256 + t] = xp[(size_t)b * str + off];
  }
  __syncthreads();  // drains x loads: vmcnt clean for the counted pipeline

  auto stage = [&](int s) {
    int buf = s % NBUF;
    int rbase = k0 + s * KSTEP + wv * 4;
#pragma unroll
    for (int rr = 0; rr < 4; rr++) {
      int r = rbase + rr;
      const float* src = (r < lenW) ? (Wmat + (size_t)r * N + colbase)
                                    : (Umat + (size_t)(r - lenW) * N + colbase);
      float* dst = &wl[(buf * KSTEP + (wv * 4 + rr)) * 256];
      if (jok) gload16(src, dst);
    }
  };

  if (nst > 0) stage(0);
  if (nst > 1) stage(1);

  float acc[8][4];
#pragma unroll
  for (int bi = 0; bi < 8; bi++)
    for (int cc = 0; cc < 4; cc++) acc[bi][cc] = 0.f;

  for (int s = 0; s < nst; s++) {
    if (s + 2 < nst) stage(s + 2);
    int ahead = nst - 1 - s; if (ahead > 2) ahead = 2;
    if (ahead == 2)      asm volatile("s_waitcnt vmcnt(8)");
    else if (ahead == 1) asm volatile("s_waitcnt vmcnt(4)");
    else                 asm volatile("s_waitcnt vmcnt(0)");
    __builtin_amdgcn_s_barrier();
    __builtin_amdgcn_sched_barrier(0);
    const float* wb = &wl[(s % NBUF) * KSTEP * 256];
    int xoff = s * KSTEP;
#pragma unroll
    for (int k4 = 0; k4 < 4; k4++) {
      float4 xv[8];
#pragma unroll
      for (int bi = 0; bi < 8; bi++)
        xv[bi] = *(const float4*)&xl[(wv * 8 + bi) * 256 + xoff + k4 * 4];
#pragma unroll
      for (int kk = 0; kk < 4; kk++) {
        float4 w = *(const float4*)&wb[(k4 * 4 + kk) * 256 + lane * 4];
#pragma unroll
        for (int bi = 0; bi < 8; bi++) {
          float xs = (&xv[bi].x)[kk];
          acc[bi][0] += xs * w.x; acc[bi][1] += xs * w.y;
          acc[bi][2] += xs * w.z; acc[bi][3] += xs * w.w;
        }
      }
    }
    asm volatile("s_waitcnt lgkmcnt(0)");
    __builtin_amdgcn_sched_barrier(0);
    __builtin_amdgcn_s_barrier();
  }

  if (jok) {
#pragma unroll
    for (int bi = 0; bi < 8; bi++) {
      int b = wv * 8 + bi;
      *(float4*)&zp[((size_t)kc * BB + b) * N + colbase] =
          make_float4(acc[bi][0], acc[bi][1], acc[bi][2], acc[bi][3]);
    }
  }
}

// ---------------- per-step small kernels ----------------

__global__ __launch_bounds__(256) void lstm_finish(const float* __restrict__ zpart,
    const float* __restrict__ bias, float* __restrict__ h, float* __restrict__ c)
{
  int b = blockIdx.x;
  int j = blockIdx.y * 256 + threadIdx.x;
  float zi = bias[j], zf = bias[LU + j], zg = bias[2 * LU + j], zo = bias[3 * LU + j];
#pragma unroll
  for (int kc = 0; kc < KS; kc++) {
    const float* zpt = zpart + ((size_t)kc * BB + b) * 4096;
    zi += zpt[j]; zf += zpt[LU + j]; zg += zpt[2 * LU + j]; zo += zpt[3 * LU + j];
  }
  float si = 1.f / (1.f + expf(-zi));
  float sf = 1.f / (1.f + expf(-zf));
  float tg = tanhf(zg);
  float so = 1.f / (1.f + expf(-zo));
  float cn = sf * c[b * LU + j] + si * tg;
  float hn = so * tanhf(cn);
  c[b * LU + j] = cn;
  h[b * LU + j] = hn;
}

__global__ __launch_bounds__(256) void pq_kernel(const float* __restrict__ h_a,
    const float* __restrict__ Wq, float* __restrict__ pq)
{
  int b = blockIdx.x; int t = threadIdx.x;
  int a = t & 127, half = t >> 7;
  const float* hp = h_a + b * LU + half * 512;
  const float* wp = Wq + (size_t)half * 512 * AA + a;
  float acc = 0.f;
#pragma unroll 8
  for (int k = 0; k < 512; k++) acc += hp[k] * wp[(size_t)k * AA];
  __shared__ float red[256];
  red[t] = acc;
  __syncthreads();
  if (t < 128) pq[b * AA + t] = red[t] + red[t + 128];
}

__global__ __launch_bounds__(256) void energy_kernel(const float* __restrict__ keys,
    const float* __restrict__ pq, const float* __restrict__ M, const float* __restrict__ ast,
    const float* __restrict__ Wv, const float* __restrict__ bv, const int* __restrict__ mlen,
    float* __restrict__ e)
{
  int stile = blockIdx.x, b = blockIdx.y;
  int t = threadIdx.x;
  int s0 = stile * 16;
  int ml = mlen[b];
  if (s0 >= ml) return;           // fully masked tile: e never read there
  __shared__ float astw[48];
  __shared__ float Ml[KK * AA];
  __shared__ float wvl[AA];
  __shared__ float pql[AA];
  if (t < 46) { int s = s0 + t - 15; astw[t] = (s >= 0 && s < SS) ? ast[b * SS + s] : 0.f; }
  if (t >= 64 && t < 192) { int a = t - 64; wvl[a] = Wv[a]; pql[a] = pq[b * AA + a]; }
  for (int i = t; i < KK * AA; i += 256) Ml[i] = M[i];
  __syncthreads();
  int sl = t >> 4, u = t & 15;
  int s = s0 + sl;
  const float* kp = keys + ((size_t)b * SS + s) * AA;
  float arg[8];
#pragma unroll
  for (int jj = 0; jj < 8; jj++) { int a = u + 16 * jj; arg[jj] = kp[a] + pql[a]; }
#pragma unroll
  for (int k = 0; k < KK; k++) {
    float aw = astw[sl + k];
#pragma unroll
    for (int jj = 0; jj < 8; jj++) arg[jj] += aw * Ml[k * AA + u + 16 * jj];
  }
  float v = 0.f;
#pragma unroll
  for (int jj = 0; jj < 8; jj++) v += tanhf(arg[jj]) * wvl[u + 16 * jj];
#pragma unroll
  for (int m = 1; m < 16; m <<= 1) v += __shfl_xor(v, m);
  if (u == 0) e[b * SS + s] = (s < ml) ? (v + bv[0]) : -1e9f;
}

__global__ __launch_bounds__(256) void softmax_kernel(const float* __restrict__ e,
    const int* __restrict__ mlen, float* __restrict__ al, float* __restrict__ ast)
{
  int b = blockIdx.x, t = threadIdx.x;
  int ml = mlen[b];
  __shared__ float red[4];
  float m = -3e38f;
  for (int s = t; s < ml; s += 256) m = fmaxf(m, e[b * SS + s]);
#pragma unroll
  for (int msk = 1; msk < 64; msk <<= 1) m = fmaxf(m, __shfl_xor(m, msk));
  if ((t & 63) == 0) red[t >> 6] = m;
  __syncthreads();
  m = fmaxf(fmaxf(red[0], red[1]), fmaxf(red[2], red[3]));
  __syncthreads();
  float sum = 0.f;
  for (int s = t; s < ml; s += 256) sum += expf(e[b * SS + s] - m);
#pragma unroll
  for (int msk = 1; msk < 64; msk <<= 1) sum += __shfl_xor(sum, msk);
  if ((t & 63) == 0) red[t >> 6] = sum;
  __syncthreads();
  float inv = 1.f / (red[0] + red[1] + red[2] + red[3]);
  for (int s = t; s < ml; s += 256) {
    float a_ = expf(e[b * SS + s] - m) * inv;
    al[b * SS + s] = a_;
    ast[b * SS + s] += a_;
  }
}

// ctx partials: block (sc, b) handles 100 s-rows x all 1024 d, skips masked rows
__global__ __launch_bounds__(256) void ctx_part(const float* __restrict__ al,
    const float* __restrict__ mem, const int* __restrict__ mlen, float* __restrict__ cp)
{
  int sc = blockIdx.x, b = blockIdx.y;
  int t = threadIdx.x;
  __shared__ float alsh[100];
  int ml = mlen[b];
  int cnt = ml - sc * 100; if (cnt > 100) cnt = 100; if (cnt < 0) cnt = 0;
  if (t < cnt) alsh[t] = al[b * SS + sc * 100 + t];
  __syncthreads();
  float4 acc = make_float4(0.f, 0.f, 0.f, 0.f);
  const float* mp = mem + ((size_t)b * SS + sc * 100) * DE + t * 4;
#pragma unroll 4
  for (int i = 0; i < cnt; i++) {
    float4 v = *(const float4*)(mp + (size_t)i * DE);
    float a_ = alsh[i];
    acc.x += a_ * v.x; acc.y += a_ * v.y; acc.z += a_ * v.z; acc.w += a_ * v.w;
  }
  *(float4*)&cp[((size_t)sc * BB + b) * DE + t * 4] = acc;
}

__global__ __launch_bounds__(256) void ctx_red(const float* __restrict__ cp,
                                               float* __restrict__ ctx)
{
  int b = blockIdx.x;
  int t = threadIdx.x;
  float4 acc = make_float4(0.f, 0.f, 0.f, 0.f);
#pragma unroll
  for (int sc = 0; sc < 16; sc++) {
    float4 v = *(const float4*)&cp[((size_t)sc * BB + b) * DE + t * 4];
    acc.x += v.x; acc.y += v.y; acc.z += v.z; acc.w += v.w;
  }
  *(float4*)&ctx[b * DE + t * 4] = acc;
}

__global__ __launch_bounds__(256) void cls_fin(const float* __restrict__ zpart,
    const float* __restrict__ bc, float* __restrict__ out, int tstep)
{
  int jb = blockIdx.x, b = blockIdx.y;
  int v = jb * 256 + threadIdx.x;
  if (v < VV) {
    float acc = bc[v];
#pragma unroll
    for (int kc = 0; kc < KS; kc++) acc += zpart[((size_t)kc * BB + b) * VV + v];
    out[(size_t)b * TT * VV + (size_t)tstep * VV + v] = acc;
  }
}

__global__ __launch_bounds__(256) void stp_kernel(const float* __restrict__ h1,
    const float* __restrict__ Ws, const float* __restrict__ bs,
    float* __restrict__ out, int tstep)
{
  int b = blockIdx.x, t = threadIdx.x;
  const float* cr = out + (size_t)b * TT * VV + (size_t)tstep * VV;
  float acc = 0.f;
  for (int k = t; k < LU; k += 256) acc += h1[b * LU + k] * Ws[k];
  for (int v = t; v < VV; v += 256) acc += cr[v] * Ws[LU + v];
#pragma unroll
  for (int msk = 1; msk < 64; msk <<= 1) acc += __shfl_xor(acc, msk);
  __shared__ float red[4];
  if ((t & 63) == 0) red[t >> 6] = acc;
  __syncthreads();
  if (t == 0) out[(size_t)BB * TT * VV + (size_t)b * TT + tstep] =
      red[0] + red[1] + red[2] + red[3] + bs[0];
}

// ---------------- launcher ----------------

extern "C" void kernel_launch(void* const* d_in, const int* in_sizes, int n_in,
                              void* d_out, int out_size, void* d_ws, size_t ws_size,
                              hipStream_t stream)
{
  const int*   tokens = (const int*)  d_in[0];
  const float* memory = (const float*)d_in[1];
  const int*   mlen   = (const int*)  d_in[2];
  const float* emb    = (const float*)d_in[3];
  const float* Wp1    = (const float*)d_in[4];
  const float* bp1    = (const float*)d_in[5];
  const float* Wp2    = (const float*)d_in[6];
  const float* bp2    = (const float*)d_in[7];
  const float* Wq     = (const float*)d_in[8];
  const float* Wmem   = (const float*)d_in[9];
  const float* convk  = (const float*)d_in[10];
  const float* Wloc   = (const float*)d_in[11];
  const float* Wv     = (const float*)d_in[12];
  const float* bv     = (const float*)d_in[13];
  const float* Wa     = (const float*)d_in[14];
  const float* Ua     = (const float*)d_in[15];
  const float* ba     = (const float*)d_in[16];
  const float* W0     = (const float*)d_in[17];
  const float* U0     = (const float*)d_in[18];
  const float* b0     = (const float*)d_in[19];
  const float* W1     = (const float*)d_in[20];
  const float* U1     = (const float*)d_in[21];
  const float* b1     = (const float*)d_in[22];
  const float* Wc     = (const float*)d_in[23];
  const float* bc     = (const float*)d_in[24];
  const float* Ws     = (const float*)d_in[25];
  const float* bs     = (const float*)d_in[26];
  float* out = (float*)d_out;
  float* ws = (float*)d_ws;

  size_t o = 0;
  float* keys  = ws + o;  o += (size_t)BB * SS * AA;
  float* M     = ws + o;  o += 4096;
  float* P_all = ws + o;  o += (size_t)TT * BB * PR;
  float* st    = ws + o;
  float* h_a = st;
  float* c_a = h_a + BB * LU;
  float* h0  = c_a + BB * LU;
  float* c0  = h0 + BB * LU;
  float* h1  = c0 + BB * LU;
  float* c1  = h1 + BB * LU;
  float* ctx = c1 + BB * LU;
  float* ast = ctx + BB * DE;
  size_t stcount = (size_t)6 * BB * LU + (size_t)BB * DE + (size_t)BB * SS;
  o += stcount;
  float* pq   = ws + o;  o += (size_t)BB * AA;
  float* ebuf = ws + o;  o += (size_t)BB * SS;
  float* al   = ws + o;  o += (size_t)BB * SS;
  float* zp   = ws + o;  o += (size_t)KS * BB * 4096;
  float* cp   = ws + o;  o += (size_t)16 * BB * DE;

  hipMemsetAsync(st, 0, stcount * sizeof(float), stream);
  keys_kernel<<<dim3(200, BB), 256, 0, stream>>>(memory, Wmem, keys);
  mconv_kernel<<<KK, AA, 0, stream>>>(convk, Wloc, M);
  prenet_all<<<dim3(TT, 2), 256, 0, stream>>>(tokens, emb, Wp1, bp1, Wp2, bp2, P_all);

  for (int tstep = 0; tstep < TT; tstep++) {
    // attention LSTM: z = [p,ctx]@Wa + h_a@Ua   (K=2304, chunk=144)
    gemv_pipe<<<dim3(16, KS), 256, 0, stream>>>(
        P_all + (size_t)tstep * BB * PR, PR, ctx, DE, h_a, LU,
        Wa, Ua, 4096, 144, zp);
    lstm_finish<<<dim3(BB, 4), 256, 0, stream>>>(zp, ba, h_a, c_a);
    pq_kernel<<<BB, 256, 0, stream>>>(h_a, Wq, pq);
    energy_kernel<<<dim3(100, BB), 256, 0, stream>>>(keys, pq, M, ast, Wv, bv, mlen, ebuf);
    softmax_kernel<<<BB, 256, 0, stream>>>(ebuf, mlen, al, ast);
    ctx_part<<<dim3(16, BB), 256, 0, stream>>>(al, memory, mlen, cp);
    ctx_red<<<BB, 256, 0, stream>>>(cp, ctx);
    // LSTM0: z = [h_a,ctx]@W0 + h0@U0   (K=3072, chunk=192)
    gemv_pipe<<<dim3(16, KS), 256, 0, stream>>>(
        h_a, LU, ctx, DE, h0, LU,
        W0, U0, 4096, 192, zp);
    lstm_finish<<<dim3(BB, 4), 256, 0, stream>>>(zp, b0, h0, c0);
    // LSTM1: z = h0@W1 + h1@U1   (K=2048, chunk=128)
    gemv_pipe<<<dim3(16, KS), 256, 0, stream>>>(
        h0, LU, h0, 0, h1, LU,
        W1, U1, 4096, 128, zp);
    lstm_finish<<<dim3(BB, 4), 256, 0, stream>>>(zp, b1, h1, c1);
    // cls = [h1,ctx]@Wc + bc   (K=2048, N=1000, chunk=128)
    gemv_pipe<<<dim3(4, KS), 256, 0, stream>>>(
        h1, LU, ctx, DE, h1, 0,
        Wc, Wc, VV, 128, zp);
    cls_fin<<<dim3(4, BB), 256, 0, stream>>>(zp, bc, out, tstep);
    stp_kernel<<<BB, 256, 0, stream>>>(h1, Ws, bs, out, tstep);
  }
}

// Round 3
// 49162.042 us; speedup vs baseline: 3.5621x; 1.0279x over previous
//
#include <hip/hip_runtime.h>

#define BB 32
#define TT 256
#define SS 1600
#define DE 1024
#define VV 1000
#define EM 512
#define PR 256
#define LU 1024
#define AA 128
#define FF 32
#define KK 31
#define KS 16      // k-split for LSTM gemvs
#define KSC 32     // k-split for cls gemv
#define KSTEP 16   // rows per stage
#define NBUF 3     // LDS ring buffers

__device__ __forceinline__ void gload16(const float* g, float* l) {
  __builtin_amdgcn_global_load_lds(
      (const __attribute__((address_space(1))) void*)g,
      (__attribute__((address_space(3))) void*)l, 16, 0, 0);
}

// ---------------- once-per-call precompute ----------------

__global__ __launch_bounds__(256) void keys_kernel(const float* __restrict__ mem,
                                                   const float* __restrict__ Wmem,
                                                   float* __restrict__ keys)
{
  int stile = blockIdx.x;           // 200 tiles of 8 s-rows
  int b = blockIdx.y;
  int t = threadIdx.x;
  __shared__ float Xt[8 * 1032];
  const float* mp = mem + ((size_t)b * SS + (size_t)stile * 8) * DE;
  for (int li = t; li < 8 * 256; li += 256) {
    int row = li >> 8, c4 = li & 255;
    float4 v = *(const float4*)(mp + row * DE + c4 * 4);
    *(float4*)(Xt + row * 1032 + c4 * 4) = v;
  }
  __syncthreads();
  int sl = t >> 5, u = t & 31;
  float acc[4] = {0.f, 0.f, 0.f, 0.f};
  for (int k = 0; k < DE; k++) {
    float x = Xt[sl * 1032 + k];
    const float* wr = Wmem + k * AA;
#pragma unroll
    for (int jj = 0; jj < 4; jj++) acc[jj] += x * wr[u + 32 * jj];
  }
  float* kp = keys + ((size_t)b * SS + (size_t)stile * 8 + sl) * AA;
#pragma unroll
  for (int jj = 0; jj < 4; jj++) kp[u + 32 * jj] = acc[jj];
}

__global__ void mconv_kernel(const float* __restrict__ ck, const float* __restrict__ Wloc,
                             float* __restrict__ M)
{
  int a = threadIdx.x;  // 128
  int k = blockIdx.x;   // 31
  float acc = 0.f;
  for (int c = 0; c < FF; c++) acc += ck[k * FF + c] * Wloc[c * AA + a];
  M[k * AA + a] = acc;
}

__global__ __launch_bounds__(256) void prenet_all(const int* __restrict__ tokens,
    const float* __restrict__ emb, const float* __restrict__ Wp1, const float* __restrict__ bp1,
    const float* __restrict__ Wp2, const float* __restrict__ bp2, float* __restrict__ P)
{
  int tstep = blockIdx.x;
  int bh = blockIdx.y;
  int t = threadIdx.x;
  __shared__ float X[16 * 512];
  __shared__ float P1[16 * 256];
  for (int li = t; li < 16 * 128; li += 256) {
    int bb = li >> 7, c4 = li & 127;
    int tok = tokens[(bh * 16 + bb) * TT + tstep];
    *(float4*)(X + bb * 512 + c4 * 4) = *(const float4*)(emb + (size_t)tok * EM + c4 * 4);
  }
  __syncthreads();
  int j = t;
  float acc[16];
#pragma unroll
  for (int i = 0; i < 16; i++) acc[i] = 0.f;
  for (int k = 0; k < EM; k++) {
    float w = Wp1[k * PR + j];
#pragma unroll
    for (int i = 0; i < 16; i++) acc[i] += X[i * 512 + k] * w;
  }
#pragma unroll
  for (int i = 0; i < 16; i++) P1[i * 256 + j] = fmaxf(acc[i] + bp1[j], 0.f);
  __syncthreads();
#pragma unroll
  for (int i = 0; i < 16; i++) acc[i] = 0.f;
  for (int k = 0; k < PR; k++) {
    float w = Wp2[k * PR + j];
#pragma unroll
    for (int i = 0; i < 16; i++) acc[i] += P1[i * 256 + k] * w;
  }
  float* outp = P + (size_t)tstep * BB * PR + (size_t)bh * 16 * PR;
#pragma unroll
  for (int i = 0; i < 16; i++) outp[i * PR + j] = fmaxf(acc[i] + bp2[j], 0.f);
}

// ---------------- deep-pipelined batched GEMV ----------------
// zpart[kc][b][j] = sum_{k in chunk} xcat[b][k] * W[k][j]
__global__ __launch_bounds__(256) void gemv_pipe(
    const float* __restrict__ x0, int len0,
    const float* __restrict__ x1, int len1,
    const float* __restrict__ x2, int len2,
    const float* __restrict__ Wmat, const float* __restrict__ Umat,
    int N, int chunk, float* __restrict__ zp)
{
  __shared__ float wl[NBUF * KSTEP * 256];   // 48 KB
  __shared__ float xl[32 * 256];             // 32 KB
  int jb = blockIdx.x, kc = blockIdx.y;
  int t = threadIdx.x;
  int lane = t & 63;
  int wv = __builtin_amdgcn_readfirstlane(t >> 6);
  int lenW = len0 + len1;
  int k0 = kc * chunk;
  int nst = chunk >> 4;
  int colbase = jb * 256 + lane * 4;
  bool jok = (colbase + 4 <= N);

  // stage x chunk into xl[b][0..chunk): wave wv handles batches wv*8..wv*8+7,
  // lanes cover k coalesced.
#pragma unroll
  for (int bi = 0; bi < 8; bi++) {
    int b = wv * 8 + bi;
    for (int kk = lane; kk < chunk; kk += 64) {
      int k = k0 + kk;
      const float* xp; int str; int off;
      if (k < len0)      { xp = x0; str = len0; off = k; }
      else if (k < lenW) { xp = x1; str = len1; off = k - len0; }
      else               { xp = x2; str = len2; off = k - lenW; }
      xl[b * 256 + kk] = xp[(size_t)b * str + off];
    }
  }
  __syncthreads();  // drains x loads: vmcnt clean for the counted pipeline

  auto stage = [&](int s) {
    int buf = s % NBUF;
    int rbase = k0 + s * KSTEP + wv * 4;
#pragma unroll
    for (int rr = 0; rr < 4; rr++) {
      int r = rbase + rr;
      const float* src = (r < lenW) ? (Wmat + (size_t)r * N + colbase)
                                    : (Umat + (size_t)(r - lenW) * N + colbase);
      float* dst = &wl[(buf * KSTEP + (wv * 4 + rr)) * 256];
      if (jok) gload16(src, dst);
    }
  };

  if (nst > 0) stage(0);
  if (nst > 1) stage(1);

  float acc[8][4];
#pragma unroll
  for (int bi = 0; bi < 8; bi++)
    for (int cc = 0; cc < 4; cc++) acc[bi][cc] = 0.f;

  for (int s = 0; s < nst; s++) {
    if (s + 2 < nst) stage(s + 2);
    int ahead = nst - 1 - s; if (ahead > 2) ahead = 2;
    if (ahead == 2)      asm volatile("s_waitcnt vmcnt(8)");
    else if (ahead == 1) asm volatile("s_waitcnt vmcnt(4)");
    else                 asm volatile("s_waitcnt vmcnt(0)");
    __builtin_amdgcn_s_barrier();
    __builtin_amdgcn_sched_barrier(0);
    const float* wb = &wl[(s % NBUF) * KSTEP * 256];
    int xoff = s * KSTEP;
#pragma unroll
    for (int k4 = 0; k4 < 4; k4++) {
      float4 xv[8];
#pragma unroll
      for (int bi = 0; bi < 8; bi++)
        xv[bi] = *(const float4*)&xl[(wv * 8 + bi) * 256 + xoff + k4 * 4];
#pragma unroll
      for (int kk = 0; kk < 4; kk++) {
        float4 w = *(const float4*)&wb[(k4 * 4 + kk) * 256 + lane * 4];
#pragma unroll
        for (int bi = 0; bi < 8; bi++) {
          float xs = (&xv[bi].x)[kk];
          acc[bi][0] += xs * w.x; acc[bi][1] += xs * w.y;
          acc[bi][2] += xs * w.z; acc[bi][3] += xs * w.w;
        }
      }
    }
    asm volatile("s_waitcnt lgkmcnt(0)");
    __builtin_amdgcn_sched_barrier(0);
    __builtin_amdgcn_s_barrier();
  }

  if (jok) {
#pragma unroll
    for (int bi = 0; bi < 8; bi++) {
      int b = wv * 8 + bi;
      *(float4*)&zp[((size_t)kc * BB + b) * N + colbase] =
          make_float4(acc[bi][0], acc[bi][1], acc[bi][2], acc[bi][3]);
    }
  }
}

// ---------------- per-step small kernels ----------------

// Reduce KS partials, apply gates, update h,c; optionally emit pq partials
// pqp[q][b][a] = sum_{j in this block's quarter} h[b,j] * Wq[j,a]
__global__ __launch_bounds__(256) void lstm_finish(const float* __restrict__ zpart,
    const float* __restrict__ bias, float* __restrict__ h, float* __restrict__ c,
    const float* __restrict__ Wq, float* __restrict__ pqp)
{
  int b = blockIdx.x;
  int q = blockIdx.y;
  int t = threadIdx.x;
  int j = q * 256 + t;
  float zi = bias[j], zf = bias[LU + j], zg = bias[2 * LU + j], zo = bias[3 * LU + j];
#pragma unroll
  for (int kc = 0; kc < KS; kc++) {
    const float* zpt = zpart + ((size_t)kc * BB + b) * 4096;
    zi += zpt[j]; zf += zpt[LU + j]; zg += zpt[2 * LU + j]; zo += zpt[3 * LU + j];
  }
  float si = 1.f / (1.f + expf(-zi));
  float sf = 1.f / (1.f + expf(-zf));
  float tg = tanhf(zg);
  float so = 1.f / (1.f + expf(-zo));
  float cn = sf * c[b * LU + j] + si * tg;
  float hn = so * tanhf(cn);
  c[b * LU + j] = cn;
  h[b * LU + j] = hn;

  if (pqp) {
    __shared__ float sh[256];
    __shared__ float sh2[256];
    sh[t] = hn;
    __syncthreads();
    int a = t & 127, half = t >> 7;
    float acc = 0.f;
    const float* wq = Wq + ((size_t)(q * 256 + half * 128)) * AA + a;
#pragma unroll 4
    for (int jj = 0; jj < 128; jj++) acc += sh[half * 128 + jj] * wq[(size_t)jj * AA];
    sh2[t] = acc;
    __syncthreads();
    if (t < 128) pqp[(size_t)q * BB * AA + b * AA + t] = sh2[t] + sh2[t + 128];
  }
}

// e[b,s] from keys + pq + location conv; also zeroes ctx (stile<4)
__global__ __launch_bounds__(256) void energy_kernel(const float* __restrict__ keys,
    const float* __restrict__ pqp, const float* __restrict__ M, const float* __restrict__ ast,
    const float* __restrict__ Wv, const float* __restrict__ bv, const int* __restrict__ mlen,
    float* __restrict__ e, float* __restrict__ ctx)
{
  int stile = blockIdx.x, b = blockIdx.y;
  int t = threadIdx.x;
  int s0 = stile * 16;
  int ml = mlen[b];
  if (stile < 4) ctx[b * DE + stile * 256 + t] = 0.f;  // rebuilt by ctx_sm_part
  if (s0 >= ml) return;
  __shared__ float astw[48];
  __shared__ float Ml[KK * AA];
  __shared__ float wvl[AA];
  __shared__ float pql[AA];
  if (t < 46) { int s = s0 + t - 15; astw[t] = (s >= 0 && s < SS) ? ast[b * SS + s] : 0.f; }
  if (t >= 64 && t < 192) {
    int a = t - 64;
    wvl[a] = Wv[a];
    pql[a] = pqp[b * AA + a] + pqp[(size_t)BB * AA + b * AA + a]
           + pqp[(size_t)2 * BB * AA + b * AA + a] + pqp[(size_t)3 * BB * AA + b * AA + a];
  }
  for (int i = t; i < KK * AA; i += 256) Ml[i] = M[i];
  __syncthreads();
  int sl = t >> 4, u = t & 15;
  int s = s0 + sl;
  const float* kp = keys + ((size_t)b * SS + s) * AA;
  float arg[8];
#pragma unroll
  for (int jj = 0; jj < 8; jj++) { int a = u + 16 * jj; arg[jj] = kp[a] + pql[a]; }
#pragma unroll
  for (int k = 0; k < KK; k++) {
    float aw = astw[sl + k];
#pragma unroll
    for (int jj = 0; jj < 8; jj++) arg[jj] += aw * Ml[k * AA + u + 16 * jj];
  }
  float v = 0.f;
#pragma unroll
  for (int jj = 0; jj < 8; jj++) v += tanhf(arg[jj]) * wvl[u + 16 * jj];
#pragma unroll
  for (int m = 1; m < 16; m <<= 1) v += __shfl_xor(v, m);
  if (u == 0) e[b * SS + s] = (s < ml) ? (v + bv[0]) : -1e9f;
}

// Fused softmax + ast update + ctx accumulation (atomic).
// Block (sc,b): recompute softmax stats for row b (cheap, L2), own 100 s-rows.
__global__ __launch_bounds__(256) void ctx_sm_part(const float* __restrict__ e,
    const int* __restrict__ mlen, const float* __restrict__ mem,
    float* __restrict__ ast, float* __restrict__ ctx)
{
  int sc = blockIdx.x, b = blockIdx.y;
  int ml = mlen[b];
  int s0 = sc * 100;
  int cnt = ml - s0; if (cnt > 100) cnt = 100;
  if (cnt <= 0) return;
  int t = threadIdx.x;
  __shared__ float red[4];
  __shared__ float alsh[100];
  const float* er = e + b * SS;
  float m = -3e38f;
  for (int s = t; s < ml; s += 256) m = fmaxf(m, er[s]);
#pragma unroll
  for (int msk = 1; msk < 64; msk <<= 1) m = fmaxf(m, __shfl_xor(m, msk));
  if ((t & 63) == 0) red[t >> 6] = m;
  __syncthreads();
  m = fmaxf(fmaxf(red[0], red[1]), fmaxf(red[2], red[3]));
  __syncthreads();
  float sum = 0.f;
  for (int s = t; s < ml; s += 256) sum += expf(er[s] - m);
#pragma unroll
  for (int msk = 1; msk < 64; msk <<= 1) sum += __shfl_xor(sum, msk);
  if ((t & 63) == 0) red[t >> 6] = sum;
  __syncthreads();
  float inv = 1.f / (red[0] + red[1] + red[2] + red[3]);
  if (t < cnt) {
    float a_ = expf(er[s0 + t] - m) * inv;
    alsh[t] = a_;
    ast[b * SS + s0 + t] += a_;
  }
  __syncthreads();
  float4 acc = make_float4(0.f, 0.f, 0.f, 0.f);
  const float* mp = mem + ((size_t)b * SS + s0) * DE + t * 4;
#pragma unroll 4
  for (int i = 0; i < cnt; i++) {
    float4 v = *(const float4*)(mp + (size_t)i * DE);
    float a_ = alsh[i];
    acc.x += a_ * v.x; acc.y += a_ * v.y; acc.z += a_ * v.z; acc.w += a_ * v.w;
  }
  float* cp = ctx + b * DE + t * 4;
  atomicAdd(cp + 0, acc.x);
  atomicAdd(cp + 1, acc.y);
  atomicAdd(cp + 2, acc.z);
  atomicAdd(cp + 3, acc.w);
}

// cls reduce + write + stop-token, fused
__global__ __launch_bounds__(256) void cls_stp(const float* __restrict__ zp,
    const float* __restrict__ bc, const float* __restrict__ h1,
    const float* __restrict__ Ws, const float* __restrict__ bs,
    float* __restrict__ out, int tstep)
{
  int b = blockIdx.x, t = threadIdx.x;
  float sacc = 0.f;
  for (int k = t; k < LU; k += 256) sacc += h1[b * LU + k] * Ws[k];
  float* orow = out + (size_t)b * TT * VV + (size_t)tstep * VV;
  for (int v = t; v < VV; v += 256) {
    float acc = bc[v];
#pragma unroll
    for (int kc = 0; kc < KSC; kc++) acc += zp[((size_t)kc * BB + b) * VV + v];
    orow[v] = acc;
    sacc += acc * Ws[LU + v];
  }
#pragma unroll
  for (int msk = 1; msk < 64; msk <<= 1) sacc += __shfl_xor(sacc, msk);
  __shared__ float red[4];
  if ((t & 63) == 0) red[t >> 6] = sacc;
  __syncthreads();
  if (t == 0) out[(size_t)BB * TT * VV + (size_t)b * TT + tstep] =
      red[0] + red[1] + red[2] + red[3] + bs[0];
}

// ---------------- launcher ----------------

extern "C" void kernel_launch(void* const* d_in, const int* in_sizes, int n_in,
                              void* d_out, int out_size, void* d_ws, size_t ws_size,
                              hipStream_t stream)
{
  const int*   tokens = (const int*)  d_in[0];
  const float* memory = (const float*)d_in[1];
  const int*   mlen   = (const int*)  d_in[2];
  const float* emb    = (const float*)d_in[3];
  const float* Wp1    = (const float*)d_in[4];
  const float* bp1    = (const float*)d_in[5];
  const float* Wp2    = (const float*)d_in[6];
  const float* bp2    = (const float*)d_in[7];
  const float* Wq     = (const float*)d_in[8];
  const float* Wmem   = (const float*)d_in[9];
  const float* convk  = (const float*)d_in[10];
  const float* Wloc   = (const float*)d_in[11];
  const float* Wv     = (const float*)d_in[12];
  const float* bv     = (const float*)d_in[13];
  const float* Wa     = (const float*)d_in[14];
  const float* Ua     = (const float*)d_in[15];
  const float* ba     = (const float*)d_in[16];
  const float* W0     = (const float*)d_in[17];
  const float* U0     = (const float*)d_in[18];
  const float* b0     = (const float*)d_in[19];
  const float* W1     = (const float*)d_in[20];
  const float* U1     = (const float*)d_in[21];
  const float* b1     = (const float*)d_in[22];
  const float* Wc     = (const float*)d_in[23];
  const float* bc     = (const float*)d_in[24];
  const float* Ws     = (const float*)d_in[25];
  const float* bs     = (const float*)d_in[26];
  float* out = (float*)d_out;
  float* ws = (float*)d_ws;

  size_t o = 0;
  float* keys  = ws + o;  o += (size_t)BB * SS * AA;
  float* M     = ws + o;  o += 4096;
  float* P_all = ws + o;  o += (size_t)TT * BB * PR;
  float* st    = ws + o;
  float* h_a = st;
  float* c_a = h_a + BB * LU;
  float* h0  = c_a + BB * LU;
  float* c0  = h0 + BB * LU;
  float* h1  = c0 + BB * LU;
  float* c1  = h1 + BB * LU;
  float* ctx = c1 + BB * LU;
  float* ast = ctx + BB * DE;
  size_t stcount = (size_t)6 * BB * LU + (size_t)BB * DE + (size_t)BB * SS;
  o += stcount;
  float* pqp  = ws + o;  o += (size_t)4 * BB * AA;
  float* ebuf = ws + o;  o += (size_t)BB * SS;
  float* zp   = ws + o;  o += (size_t)KS * BB * 4096;

  hipMemsetAsync(st, 0, stcount * sizeof(float), stream);
  keys_kernel<<<dim3(200, BB), 256, 0, stream>>>(memory, Wmem, keys);
  mconv_kernel<<<KK, AA, 0, stream>>>(convk, Wloc, M);
  prenet_all<<<dim3(TT, 2), 256, 0, stream>>>(tokens, emb, Wp1, bp1, Wp2, bp2, P_all);

  for (int tstep = 0; tstep < TT; tstep++) {
    // attention LSTM: z = [p,ctx]@Wa + h_a@Ua   (K=2304, chunk=144)
    gemv_pipe<<<dim3(16, KS), 256, 0, stream>>>(
        P_all + (size_t)tstep * BB * PR, PR, ctx, DE, h_a, LU,
        Wa, Ua, 4096, 144, zp);
    lstm_finish<<<dim3(BB, 4), 256, 0, stream>>>(zp, ba, h_a, c_a, Wq, pqp);
    energy_kernel<<<dim3(100, BB), 256, 0, stream>>>(keys, pqp, M, ast, Wv, bv, mlen,
                                                     ebuf, ctx);
    ctx_sm_part<<<dim3(16, BB), 256, 0, stream>>>(ebuf, mlen, memory, ast, ctx);
    // LSTM0: z = [h_a,ctx]@W0 + h0@U0   (K=3072, chunk=192)
    gemv_pipe<<<dim3(16, KS), 256, 0, stream>>>(
        h_a, LU, ctx, DE, h0, LU,
        W0, U0, 4096, 192, zp);
    lstm_finish<<<dim3(BB, 4), 256, 0, stream>>>(zp, b0, h0, c0, Wq, nullptr);
    // LSTM1: z = h0@W1 + h1@U1   (K=2048, chunk=128)
    gemv_pipe<<<dim3(16, KS), 256, 0, stream>>>(
        h0, LU, h0, 0, h1, LU,
        W1, U1, 4096, 128, zp);
    lstm_finish<<<dim3(BB, 4), 256, 0, stream>>>(zp, b1, h1, c1, Wq, nullptr);
    // cls = [h1,ctx]@Wc + bc   (K=2048, N=1000, chunk=64, KSC=32)
    gemv_pipe<<<dim3(4, KSC), 256, 0, stream>>>(
        h1, LU, ctx, DE, h1, 0,
        Wc, Wc, VV, 64, zp);
    cls_stp<<<BB, 256, 0, stream>>>(zp, bc, h1, Ws, bs, out, tstep);
  }
}

// Round 4
// 43474.622 us; speedup vs baseline: 4.0281x; 1.1308x over previous
//
#include <hip/hip_runtime.h>

#define BB 32
#define TT 256
#define SS 1600
#define DE 1024
#define VV 1000
#define EM 512
#define PR 256
#define LU 1024
#define AA 128
#define FF 32
#define KK 31
#define KSC 32     // k-split for cls gemv
#define KSTEP 16   // rows per stage (fp32 gemv)
#define NBUF 3     // LDS ring buffers (fp32 gemv)

typedef __attribute__((ext_vector_type(8))) short short8;
typedef __attribute__((ext_vector_type(4))) float f32x4;

__device__ __forceinline__ float bf2f(ushort u) {
  unsigned int x = ((unsigned int)u) << 16;
  return __builtin_bit_cast(float, x);
}
__device__ __forceinline__ ushort f2bf(float f) {
  unsigned int x = __builtin_bit_cast(unsigned int, f);
  return (ushort)((x + 0x7FFFu + ((x >> 16) & 1u)) >> 16);
}
__device__ __forceinline__ void gload16(const void* g, void* l) {
  __builtin_amdgcn_global_load_lds(
      (const __attribute__((address_space(1))) void*)g,
      (__attribute__((address_space(3))) void*)l, 16, 0, 0);
}

// ---------------- once-per-call precompute ----------------

__global__ __launch_bounds__(256) void conv_mem(const float* __restrict__ in,
                                                ushort* __restrict__ out, int n4)
{
  int i = blockIdx.x * 256 + threadIdx.x;
  if (i < n4) {
    float4 v = *(const float4*)(in + (size_t)i * 4);
    ushort4 o;
    o.x = f2bf(v.x); o.y = f2bf(v.y); o.z = f2bf(v.z); o.w = f2bf(v.w);
    *(ushort4*)(out + (size_t)i * 4) = o;
  }
}

// Pack [Wm;Um] (K x 4096 fp32) into bf16 MFMA tile layout [jb][S][kg][c][e]
// (S = k/32, kg = (k%32)/8, e = k%8, c = j%128, jb = j/128)
__global__ __launch_bounds__(256) void pack_wu(const float* __restrict__ Wm,
    const float* __restrict__ Um, int lenW, ushort* __restrict__ out, int nS)
{
  int bid = blockIdx.x;
  int kg = bid & 3, S = (bid >> 2) % nS, jb = (bid >> 2) / nS;
  int t = threadIdx.x;
  int c = t >> 1, e4 = (t & 1) * 4;
  int kbase = S * 32 + kg * 8 + e4;
  int j = jb * 128 + c;
  ushort* op = out + ((size_t)(jb * nS + S) * 4 + kg) * 1024 + c * 8 + e4;
#pragma unroll
  for (int i = 0; i < 4; i++) {
    int k = kbase + i;
    float v = (k < lenW) ? Wm[(size_t)k * 4096 + j] : Um[(size_t)(k - lenW) * 4096 + j];
    op[i] = f2bf(v);
  }
}

__global__ __launch_bounds__(256) void keys_kernel(const float* __restrict__ mem,
                                                   const float* __restrict__ Wmem,
                                                   float* __restrict__ keys)
{
  int stile = blockIdx.x;
  int b = blockIdx.y;
  int t = threadIdx.x;
  __shared__ float Xt[8 * 1032];
  const float* mp = mem + ((size_t)b * SS + (size_t)stile * 8) * DE;
  for (int li = t; li < 8 * 256; li += 256) {
    int row = li >> 8, c4 = li & 255;
    float4 v = *(const float4*)(mp + row * DE + c4 * 4);
    *(float4*)(Xt + row * 1032 + c4 * 4) = v;
  }
  __syncthreads();
  int sl = t >> 5, u = t & 31;
  float acc[4] = {0.f, 0.f, 0.f, 0.f};
  for (int k = 0; k < DE; k++) {
    float x = Xt[sl * 1032 + k];
    const float* wr = Wmem + k * AA;
#pragma unroll
    for (int jj = 0; jj < 4; jj++) acc[jj] += x * wr[u + 32 * jj];
  }
  float* kp = keys + ((size_t)b * SS + (size_t)stile * 8 + sl) * AA;
#pragma unroll
  for (int jj = 0; jj < 4; jj++) kp[u + 32 * jj] = acc[jj];
}

__global__ void mconv_kernel(const float* __restrict__ ck, const float* __restrict__ Wloc,
                             float* __restrict__ M)
{
  int a = threadIdx.x;
  int k = blockIdx.x;
  float acc = 0.f;
  for (int c = 0; c < FF; c++) acc += ck[k * FF + c] * Wloc[c * AA + a];
  M[k * AA + a] = acc;
}

__global__ __launch_bounds__(256) void prenet_all(const int* __restrict__ tokens,
    const float* __restrict__ emb, const float* __restrict__ Wp1, const float* __restrict__ bp1,
    const float* __restrict__ Wp2, const float* __restrict__ bp2, float* __restrict__ P)
{
  int tstep = blockIdx.x;
  int bh = blockIdx.y;
  int t = threadIdx.x;
  __shared__ float X[16 * 512];
  __shared__ float P1[16 * 256];
  for (int li = t; li < 16 * 128; li += 256) {
    int bb = li >> 7, c4 = li & 127;
    int tok = tokens[(bh * 16 + bb) * TT + tstep];
    *(float4*)(X + bb * 512 + c4 * 4) = *(const float4*)(emb + (size_t)tok * EM + c4 * 4);
  }
  __syncthreads();
  int j = t;
  float acc[16];
#pragma unroll
  for (int i = 0; i < 16; i++) acc[i] = 0.f;
  for (int k = 0; k < EM; k++) {
    float w = Wp1[k * PR + j];
#pragma unroll
    for (int i = 0; i < 16; i++) acc[i] += X[i * 512 + k] * w;
  }
#pragma unroll
  for (int i = 0; i < 16; i++) P1[i * 256 + j] = fmaxf(acc[i] + bp1[j], 0.f);
  __syncthreads();
#pragma unroll
  for (int i = 0; i < 16; i++) acc[i] = 0.f;
  for (int k = 0; k < PR; k++) {
    float w = Wp2[k * PR + j];
#pragma unroll
    for (int i = 0; i < 16; i++) acc[i] += P1[i * 256 + k] * w;
  }
  float* outp = P + (size_t)tstep * BB * PR + (size_t)bh * 16 * PR;
#pragma unroll
  for (int i = 0; i < 16; i++) outp[i * PR + j] = fmaxf(acc[i] + bp2[j], 0.f);
}

// ---------------- MFMA bf16 batched GEMM: zp[kc][b][j] = x[b,kchunk]@WU[kchunk,4096]
// WUP pre-packed tile layout; x (3 fp32 segments) staged to LDS bf16.
__global__ __launch_bounds__(256) void gemm_mfma(
    const float* __restrict__ x0, int len0,
    const float* __restrict__ x1, int len1,
    const float* __restrict__ x2, int len2,
    const ushort* __restrict__ WUP, int nS, int chunk,
    float* __restrict__ zp)
{
  __shared__ alignas(16) ushort wlT[3 * 8192];   // 3 bufs x 16KB (64 k-rows x 128 cols)
  __shared__ alignas(16) ushort xl[32 * 392];    // 32 batches x PADK bf16
  const int jb = blockIdx.x, kc = blockIdx.y;
  const int t = threadIdx.x;
  const int lane = t & 63;
  const int wv = __builtin_amdgcn_readfirstlane(t >> 6);
  const int PADK = chunk + 8;                    // granule-odd row stride
  const int nst = chunk >> 6;                    // 64-k stages
  const int k0 = kc * chunk;
  const int S0 = k0 >> 5;
  const size_t jbS = (size_t)jb * nS;
  const int lenW01 = len0 + len1;

  auto stage = [&](int s) {
    int buf = s % 3;
    int Sb = S0 + s * 2;
#pragma unroll
    for (int sub = 0; sub < 4; sub++) {
      int inst = wv * 4 + sub;
      const ushort* src = WUP + (jbS + Sb + (inst >> 3)) * 4096
                        + (size_t)(((inst & 7) * 64 + lane) * 8);
      ushort* dst = wlT + buf * 8192 + inst * 512;
      gload16(src, dst);
    }
  };

  stage(0);
  stage(1);

  // x staging: fp32 -> bf16 (latency hidden under the B prefetch above)
  for (int b = 0; b < 32; b++) {
    for (int kk = t; kk < chunk; kk += 256) {
      int k = k0 + kk;
      const float* xp; int str; int off;
      if (k < len0)        { xp = x0; str = len0; off = k; }
      else if (k < lenW01) { xp = x1; str = len1; off = k - len0; }
      else                 { xp = x2; str = len2; off = k - lenW01; }
      xl[b * PADK + kk] = f2bf(xp[(size_t)b * str + off]);
    }
  }
  __syncthreads();   // drains ALL vmcnt (x loads + stage 0,1) -> counts below exact

  f32x4 acc[2][2];
#pragma unroll
  for (int mt = 0; mt < 2; mt++)
#pragma unroll
    for (int nt = 0; nt < 2; nt++)
#pragma unroll
      for (int r = 0; r < 4; r++) acc[mt][nt][r] = 0.f;

  const int lane15 = lane & 15, kg = lane >> 4;

  for (int s = 0; s < nst; s++) {
    if (s + 2 < nst) stage(s + 2);
    int ahead = nst - 1 - s; if (ahead > 2) ahead = 2;
    if (ahead == 2)      asm volatile("s_waitcnt vmcnt(8)");
    else if (ahead == 1) asm volatile("s_waitcnt vmcnt(4)");
    else                 asm volatile("s_waitcnt vmcnt(0)");
    __builtin_amdgcn_s_barrier();
    __builtin_amdgcn_sched_barrier(0);
    const ushort* bb = wlT + (s % 3) * 8192 + kg * 1024 + (wv * 32 + lane15) * 8;
    const ushort* ab = xl + lane15 * PADK + s * 64 + kg * 8;
#pragma unroll
    for (int kh = 0; kh < 2; kh++) {
      short8 b0 = *(const short8*)(bb + kh * 4096);
      short8 b1 = *(const short8*)(bb + kh * 4096 + 128);
      short8 a0 = *(const short8*)(ab + kh * 32);
      short8 a1 = *(const short8*)(ab + kh * 32 + 16 * PADK);
      acc[0][0] = __builtin_amdgcn_mfma_f32_16x16x32_bf16(a0, b0, acc[0][0], 0, 0, 0);
      acc[0][1] = __builtin_amdgcn_mfma_f32_16x16x32_bf16(a0, b1, acc[0][1], 0, 0, 0);
      acc[1][0] = __builtin_amdgcn_mfma_f32_16x16x32_bf16(a1, b0, acc[1][0], 0, 0, 0);
      acc[1][1] = __builtin_amdgcn_mfma_f32_16x16x32_bf16(a1, b1, acc[1][1], 0, 0, 0);
    }
    asm volatile("s_waitcnt lgkmcnt(0)");
    __builtin_amdgcn_sched_barrier(0);
    __builtin_amdgcn_s_barrier();
  }

  // C/D layout (HW-verified): col = lane&15, row = (lane>>4)*4 + reg
  int colb = jb * 128 + wv * 32 + lane15;
  int rowb = kg * 4;
#pragma unroll
  for (int mt = 0; mt < 2; mt++)
#pragma unroll
    for (int nt = 0; nt < 2; nt++)
#pragma unroll
      for (int r = 0; r < 4; r++) {
        int b = mt * 16 + rowb + r;
        zp[((size_t)kc * BB + b) * 4096 + colb + nt * 16] = acc[mt][nt][r];
      }
}

// ---------------- fp32 deep-pipelined GEMV (cls layer only) ----------------
__global__ __launch_bounds__(256) void gemv_pipe(
    const float* __restrict__ x0, int len0,
    const float* __restrict__ x1, int len1,
    const float* __restrict__ x2, int len2,
    const float* __restrict__ Wmat, const float* __restrict__ Umat,
    int N, int chunk, float* __restrict__ zp)
{
  __shared__ float wl[NBUF * KSTEP * 256];
  __shared__ float xl[32 * 256];
  int jb = blockIdx.x, kc = blockIdx.y;
  int t = threadIdx.x;
  int lane = t & 63;
  int wv = __builtin_amdgcn_readfirstlane(t >> 6);
  int lenW = len0 + len1;
  int k0 = kc * chunk;
  int nst = chunk >> 4;
  int colbase = jb * 256 + lane * 4;
  bool jok = (colbase + 4 <= N);

#pragma unroll
  for (int bi = 0; bi < 8; bi++) {
    int b = wv * 8 + bi;
    for (int kk = lane; kk < chunk; kk += 64) {
      int k = k0 + kk;
      const float* xp; int str; int off;
      if (k < len0)      { xp = x0; str = len0; off = k; }
      else if (k < lenW) { xp = x1; str = len1; off = k - len0; }
      else               { xp = x2; str = len2; off = k - lenW; }
      xl[b * 256 + kk] = xp[(size_t)b * str + off];
    }
  }
  __syncthreads();

  auto stage = [&](int s) {
    int buf = s % NBUF;
    int rbase = k0 + s * KSTEP + wv * 4;
#pragma unroll
    for (int rr = 0; rr < 4; rr++) {
      int r = rbase + rr;
      const float* src = (r < lenW) ? (Wmat + (size_t)r * N + colbase)
                                    : (Umat + (size_t)(r - lenW) * N + colbase);
      float* dst = &wl[(buf * KSTEP + (wv * 4 + rr)) * 256];
      if (jok) gload16(src, dst);
    }
  };

  if (nst > 0) stage(0);
  if (nst > 1) stage(1);

  float acc[8][4];
#pragma unroll
  for (int bi = 0; bi < 8; bi++)
    for (int cc = 0; cc < 4; cc++) acc[bi][cc] = 0.f;

  for (int s = 0; s < nst; s++) {
    if (s + 2 < nst) stage(s + 2);
    int ahead = nst - 1 - s; if (ahead > 2) ahead = 2;
    if (ahead == 2)      asm volatile("s_waitcnt vmcnt(8)");
    else if (ahead == 1) asm volatile("s_waitcnt vmcnt(4)");
    else                 asm volatile("s_waitcnt vmcnt(0)");
    __builtin_amdgcn_s_barrier();
    __builtin_amdgcn_sched_barrier(0);
    const float* wb = &wl[(s % NBUF) * KSTEP * 256];
    int xoff = s * KSTEP;
#pragma unroll
    for (int k4 = 0; k4 < 4; k4++) {
      float4 xv[8];
#pragma unroll
      for (int bi = 0; bi < 8; bi++)
        xv[bi] = *(const float4*)&xl[(wv * 8 + bi) * 256 + xoff + k4 * 4];
#pragma unroll
      for (int kk = 0; kk < 4; kk++) {
        float4 w = *(const float4*)&wb[(k4 * 4 + kk) * 256 + lane * 4];
#pragma unroll
        for (int bi = 0; bi < 8; bi++) {
          float xs = (&xv[bi].x)[kk];
          acc[bi][0] += xs * w.x; acc[bi][1] += xs * w.y;
          acc[bi][2] += xs * w.z; acc[bi][3] += xs * w.w;
        }
      }
    }
    asm volatile("s_waitcnt lgkmcnt(0)");
    __builtin_amdgcn_sched_barrier(0);
    __builtin_amdgcn_s_barrier();
  }

  if (jok) {
#pragma unroll
    for (int bi = 0; bi < 8; bi++) {
      int b = wv * 8 + bi;
      *(float4*)&zp[((size_t)kc * BB + b) * N + colbase] =
          make_float4(acc[bi][0], acc[bi][1], acc[bi][2], acc[bi][3]);
    }
  }
}

// ---------------- per-step small kernels ----------------

__global__ __launch_bounds__(256) void lstm_finish(const float* __restrict__ zpart,
    int nkc, const float* __restrict__ bias, float* __restrict__ h, float* __restrict__ c,
    const float* __restrict__ Wq, float* __restrict__ pqp)
{
  int b = blockIdx.x;
  int q = blockIdx.y;
  int t = threadIdx.x;
  int j = q * 256 + t;
  float zi = bias[j], zf = bias[LU + j], zg = bias[2 * LU + j], zo = bias[3 * LU + j];
  for (int kc = 0; kc < nkc; kc++) {
    const float* zpt = zpart + ((size_t)kc * BB + b) * 4096;
    zi += zpt[j]; zf += zpt[LU + j]; zg += zpt[2 * LU + j]; zo += zpt[3 * LU + j];
  }
  float si = 1.f / (1.f + expf(-zi));
  float sf = 1.f / (1.f + expf(-zf));
  float tg = tanhf(zg);
  float so = 1.f / (1.f + expf(-zo));
  float cn = sf * c[b * LU + j] + si * tg;
  float hn = so * tanhf(cn);
  c[b * LU + j] = cn;
  h[b * LU + j] = hn;

  if (pqp) {
    __shared__ float sh[256];
    __shared__ float sh2[256];
    sh[t] = hn;
    __syncthreads();
    int a = t & 127, half = t >> 7;
    float acc = 0.f;
    const float* wq = Wq + ((size_t)(q * 256 + half * 128)) * AA + a;
#pragma unroll 4
    for (int jj = 0; jj < 128; jj++) acc += sh[half * 128 + jj] * wq[(size_t)jj * AA];
    sh2[t] = acc;
    __syncthreads();
    if (t < 128) pqp[(size_t)q * BB * AA + b * AA + t] = sh2[t] + sh2[t + 128];
  }
}

__global__ __launch_bounds__(256) void energy_kernel(const float* __restrict__ keys,
    const float* __restrict__ pqp, const float* __restrict__ M, const float* __restrict__ ast,
    const float* __restrict__ Wv, const float* __restrict__ bv, const int* __restrict__ mlen,
    float* __restrict__ e, float* __restrict__ ctx)
{
  int stile = blockIdx.x, b = blockIdx.y;
  int t = threadIdx.x;
  int s0 = stile * 16;
  int ml = mlen[b];
  if (stile < 4) ctx[b * DE + stile * 256 + t] = 0.f;  // rebuilt by ctx_sm_part
  if (s0 >= ml) return;
  __shared__ float astw[48];
  __shared__ float Ml[KK * AA];
  __shared__ float wvl[AA];
  __shared__ float pql[AA];
  if (t < 46) { int s = s0 + t - 15; astw[t] = (s >= 0 && s < SS) ? ast[b * SS + s] : 0.f; }
  if (t >= 64 && t < 192) {
    int a = t - 64;
    wvl[a] = Wv[a];
    pql[a] = pqp[b * AA + a] + pqp[(size_t)BB * AA + b * AA + a]
           + pqp[(size_t)2 * BB * AA + b * AA + a] + pqp[(size_t)3 * BB * AA + b * AA + a];
  }
  for (int i = t; i < KK * AA; i += 256) Ml[i] = M[i];
  __syncthreads();
  int sl = t >> 4, u = t & 15;
  int s = s0 + sl;
  const float* kp = keys + ((size_t)b * SS + s) * AA;
  float arg[8];
#pragma unroll
  for (int jj = 0; jj < 8; jj++) { int a = u + 16 * jj; arg[jj] = kp[a] + pql[a]; }
#pragma unroll
  for (int k = 0; k < KK; k++) {
    float aw = astw[sl + k];
#pragma unroll
    for (int jj = 0; jj < 8; jj++) arg[jj] += aw * Ml[k * AA + u + 16 * jj];
  }
  float v = 0.f;
#pragma unroll
  for (int jj = 0; jj < 8; jj++) v += tanhf(arg[jj]) * wvl[u + 16 * jj];
#pragma unroll
  for (int m = 1; m < 16; m <<= 1) v += __shfl_xor(v, m);
  if (u == 0) e[b * SS + s] = (s < ml) ? (v + bv[0]) : -1e9f;
}

// softmax (recomputed per block) + ast update + ctx accumulation from bf16 memory
__global__ __launch_bounds__(256) void ctx_sm_part(const float* __restrict__ e,
    const int* __restrict__ mlen, const ushort* __restrict__ mem_bf,
    float* __restrict__ ast, float* __restrict__ ctx)
{
  int sc = blockIdx.x, b = blockIdx.y;
  int ml = mlen[b];
  int s0 = sc * 100;
  int cnt = ml - s0; if (cnt > 100) cnt = 100;
  if (cnt <= 0) return;
  int t = threadIdx.x;
  __shared__ float red[4];
  __shared__ float alsh[100];
  const float* er = e + b * SS;
  float m = -3e38f;
  for (int s = t; s < ml; s += 256) m = fmaxf(m, er[s]);
#pragma unroll
  for (int msk = 1; msk < 64; msk <<= 1) m = fmaxf(m, __shfl_xor(m, msk));
  if ((t & 63) == 0) red[t >> 6] = m;
  __syncthreads();
  m = fmaxf(fmaxf(red[0], red[1]), fmaxf(red[2], red[3]));
  __syncthreads();
  float sum = 0.f;
  for (int s = t; s < ml; s += 256) sum += expf(er[s] - m);
#pragma unroll
  for (int msk = 1; msk < 64; msk <<= 1) sum += __shfl_xor(sum, msk);
  if ((t & 63) == 0) red[t >> 6] = sum;
  __syncthreads();
  float inv = 1.f / (red[0] + red[1] + red[2] + red[3]);
  if (t < cnt) {
    float a_ = expf(er[s0 + t] - m) * inv;
    alsh[t] = a_;
    ast[b * SS + s0 + t] += a_;
  }
  __syncthreads();
  float4 acc = make_float4(0.f, 0.f, 0.f, 0.f);
  const ushort* mp = mem_bf + ((size_t)b * SS + s0) * DE + t * 4;
#pragma unroll 4
  for (int i = 0; i < cnt; i++) {
    uint2 v = *(const uint2*)(mp + (size_t)i * DE);
    float a_ = alsh[i];
    acc.x += a_ * bf2f((ushort)(v.x & 0xffff));
    acc.y += a_ * bf2f((ushort)(v.x >> 16));
    acc.z += a_ * bf2f((ushort)(v.y & 0xffff));
    acc.w += a_ * bf2f((ushort)(v.y >> 16));
  }
  float* cp = ctx + b * DE + t * 4;
  atomicAdd(cp + 0, acc.x);
  atomicAdd(cp + 1, acc.y);
  atomicAdd(cp + 2, acc.z);
  atomicAdd(cp + 3, acc.w);
}

__global__ __launch_bounds__(256) void cls_stp(const float* __restrict__ zp,
    const float* __restrict__ bc, const float* __restrict__ h1,
    const float* __restrict__ Ws, const float* __restrict__ bs,
    float* __restrict__ out, int tstep)
{
  int b = blockIdx.x, t = threadIdx.x;
  float sacc = 0.f;
  for (int k = t; k < LU; k += 256) sacc += h1[b * LU + k] * Ws[k];
  float* orow = out + (size_t)b * TT * VV + (size_t)tstep * VV;
  for (int v = t; v < VV; v += 256) {
    float acc = bc[v];
#pragma unroll
    for (int kc = 0; kc < KSC; kc++) acc += zp[((size_t)kc * BB + b) * VV + v];
    orow[v] = acc;
    sacc += acc * Ws[LU + v];
  }
#pragma unroll
  for (int msk = 1; msk < 64; msk <<= 1) sacc += __shfl_xor(sacc, msk);
  __shared__ float red[4];
  if ((t & 63) == 0) red[t >> 6] = sacc;
  __syncthreads();
  if (t == 0) out[(size_t)BB * TT * VV + (size_t)b * TT + tstep] =
      red[0] + red[1] + red[2] + red[3] + bs[0];
}

// ---------------- launcher ----------------

extern "C" void kernel_launch(void* const* d_in, const int* in_sizes, int n_in,
                              void* d_out, int out_size, void* d_ws, size_t ws_size,
                              hipStream_t stream)
{
  const int*   tokens = (const int*)  d_in[0];
  const float* memory = (const float*)d_in[1];
  const int*   mlen   = (const int*)  d_in[2];
  const float* emb    = (const float*)d_in[3];
  const float* Wp1    = (const float*)d_in[4];
  const float* bp1    = (const float*)d_in[5];
  const float* Wp2    = (const float*)d_in[6];
  const float* bp2    = (const float*)d_in[7];
  const float* Wq     = (const float*)d_in[8];
  const float* Wmem   = (const float*)d_in[9];
  const float* convk  = (const float*)d_in[10];
  const float* Wloc   = (const float*)d_in[11];
  const float* Wv     = (const float*)d_in[12];
  const float* bv     = (const float*)d_in[13];
  const float* Wa     = (const float*)d_in[14];
  const float* Ua     = (const float*)d_in[15];
  const float* ba     = (const float*)d_in[16];
  const float* W0     = (const float*)d_in[17];
  const float* U0     = (const float*)d_in[18];
  const float* b0     = (const float*)d_in[19];
  const float* W1     = (const float*)d_in[20];
  const float* U1     = (const float*)d_in[21];
  const float* b1     = (const float*)d_in[22];
  const float* Wc     = (const float*)d_in[23];
  const float* bc     = (const float*)d_in[24];
  const float* Ws     = (const float*)d_in[25];
  const float* bs     = (const float*)d_in[26];
  float* out = (float*)d_out;
  float* ws = (float*)d_ws;

  size_t o = 0;
  float* keys  = ws + o;  o += (size_t)BB * SS * AA;     // 6,553,600
  float* M     = ws + o;  o += 4096;
  float* P_all = ws + o;  o += (size_t)TT * BB * PR;     // 2,097,152
  float* st    = ws + o;
  float* h_a = st;
  float* c_a = h_a + BB * LU;
  float* h0  = c_a + BB * LU;
  float* c0  = h0 + BB * LU;
  float* h1  = c0 + BB * LU;
  float* c1  = h1 + BB * LU;
  float* ctx = c1 + BB * LU;
  float* ast = ctx + BB * DE;
  size_t stcount = (size_t)6 * BB * LU + (size_t)BB * DE + (size_t)BB * SS;
  o += stcount;
  float* pqp  = ws + o;  o += (size_t)4 * BB * AA;
  float* ebuf = ws + o;  o += (size_t)BB * SS;
  float* zp   = ws + o;  o += (size_t)9 * BB * 4096;     // max k-split partials
  ushort* mem_bf = (ushort*)(ws + o);  o += (size_t)BB * SS * DE / 2;       // 52.4M bf16
  ushort* WUPa   = (ushort*)(ws + o);  o += (size_t)2304 * 4096 / 2;
  ushort* WUP0   = (ushort*)(ws + o);  o += (size_t)3072 * 4096 / 2;
  ushort* WUP1   = (ushort*)(ws + o);  o += (size_t)2048 * 4096 / 2;

  hipMemsetAsync(st, 0, stcount * sizeof(float), stream);
  conv_mem<<<(BB * SS * DE / 4 + 255) / 256, 256, 0, stream>>>(memory, mem_bf,
                                                               BB * SS * DE / 4);
  pack_wu<<<32 * 72 * 4, 256, 0, stream>>>(Wa, Ua, PR + DE, WUPa, 72);   // K=2304
  pack_wu<<<32 * 96 * 4, 256, 0, stream>>>(W0, U0, LU + DE, WUP0, 96);   // K=3072
  pack_wu<<<32 * 64 * 4, 256, 0, stream>>>(W1, U1, LU,      WUP1, 64);   // K=2048
  keys_kernel<<<dim3(200, BB), 256, 0, stream>>>(memory, Wmem, keys);
  mconv_kernel<<<KK, AA, 0, stream>>>(convk, Wloc, M);
  prenet_all<<<dim3(TT, 2), 256, 0, stream>>>(tokens, emb, Wp1, bp1, Wp2, bp2, P_all);

  for (int tstep = 0; tstep < TT; tstep++) {
    // attention LSTM: [p,ctx]@Wa + h_a@Ua   K=2304, KS=9, chunk=256
    gemm_mfma<<<dim3(32, 9), 256, 0, stream>>>(
        P_all + (size_t)tstep * BB * PR, PR, ctx, DE, h_a, LU, WUPa, 72, 256, zp);
    lstm_finish<<<dim3(BB, 4), 256, 0, stream>>>(zp, 9, ba, h_a, c_a, Wq, pqp);
    energy_kernel<<<dim3(100, BB), 256, 0, stream>>>(keys, pqp, M, ast, Wv, bv, mlen,
                                                     ebuf, ctx);
    ctx_sm_part<<<dim3(16, BB), 256, 0, stream>>>(ebuf, mlen, mem_bf, ast, ctx);
    // LSTM0: [h_a,ctx]@W0 + h0@U0   K=3072, KS=8, chunk=384
    gemm_mfma<<<dim3(32, 8), 256, 0, stream>>>(
        h_a, LU, ctx, DE, h0, LU, WUP0, 96, 384, zp);
    lstm_finish<<<dim3(BB, 4), 256, 0, stream>>>(zp, 8, b0, h0, c0, Wq, nullptr);
    // LSTM1: h0@W1 + h1@U1   K=2048, KS=8, chunk=256
    gemm_mfma<<<dim3(32, 8), 256, 0, stream>>>(
        h0, LU, h1, LU, h0, 0, WUP1, 64, 256, zp);
    lstm_finish<<<dim3(BB, 4), 256, 0, stream>>>(zp, 8, b1, h1, c1, Wq, nullptr);
    // cls = [h1,ctx]@Wc + bc (fp32 path for precision)
    gemv_pipe<<<dim3(4, KSC), 256, 0, stream>>>(
        h1, LU, ctx, DE, h1, 0, Wc, Wc, VV, 64, zp);
    cls_stp<<<BB, 256, 0, stream>>>(zp, bc, h1, Ws, bs, out, tstep);
  }
}

// Round 5
// 41152.893 us; speedup vs baseline: 4.2554x; 1.0564x over previous
//
#include <hip/hip_runtime.h>

#define BB 32
#define TT 256
#define SS 1600
#define DE 1024
#define VV 1000
#define EM 512
#define PR 256
#define LU 1024
#define AA 128
#define FF 32
#define KK 31
#define KSC 32     // k-split for cls gemv
#define KSTEP 16   // rows per stage (fp32 gemv)
#define NBUF 3     // LDS ring buffers

typedef __attribute__((ext_vector_type(8))) short short8;
typedef __attribute__((ext_vector_type(4))) float f32x4;

__device__ __forceinline__ float bf2f(ushort u) {
  unsigned int x = ((unsigned int)u) << 16;
  return __builtin_bit_cast(float, x);
}
__device__ __forceinline__ ushort f2bf(float f) {
  unsigned int x = __builtin_bit_cast(unsigned int, f);
  return (ushort)((x + 0x7FFFu + ((x >> 16) & 1u)) >> 16);
}
__device__ __forceinline__ void gload16(const void* g, void* l) {
  __builtin_amdgcn_global_load_lds(
      (const __attribute__((address_space(1))) void*)g,
      (__attribute__((address_space(3))) void*)l, 16, 0, 0);
}
__device__ __forceinline__ float ftanh(float x) {
  float e = __expf(2.f * x);
  return 1.f - 2.f / (e + 1.f);
}
__device__ __forceinline__ float fsig(float x) {
  return 1.f / (1.f + __expf(-x));
}

// ---------------- once-per-call precompute ----------------

__global__ __launch_bounds__(256) void conv_mem(const float* __restrict__ in,
                                                ushort* __restrict__ out, int n4)
{
  int i = blockIdx.x * 256 + threadIdx.x;
  if (i < n4) {
    float4 v = *(const float4*)(in + (size_t)i * 4);
    ushort4 o;
    o.x = f2bf(v.x); o.y = f2bf(v.y); o.z = f2bf(v.z); o.w = f2bf(v.w);
    *(ushort4*)(out + (size_t)i * 4) = o;
  }
}

// Pack [Wm;Um] into bf16 MFMA tile layout [jb][S][kg][c][e]; zero-pad k>=ktot.
__global__ __launch_bounds__(256) void pack_wu(const float* __restrict__ Wm,
    const float* __restrict__ Um, int lenW, int ktot, ushort* __restrict__ out, int nS)
{
  int bid = blockIdx.x;
  int kg = bid & 3, S = (bid >> 2) % nS, jb = (bid >> 2) / nS;
  int t = threadIdx.x;
  int c = t >> 1, e4 = (t & 1) * 4;
  int kbase = S * 32 + kg * 8 + e4;
  int j = jb * 128 + c;
  ushort* op = out + ((size_t)(jb * nS + S) * 4 + kg) * 1024 + c * 8 + e4;
#pragma unroll
  for (int i = 0; i < 4; i++) {
    int k = kbase + i;
    float v = 0.f;
    if (k < lenW)      v = Wm[(size_t)k * 4096 + j];
    else if (k < ktot) v = Um[(size_t)(k - lenW) * 4096 + j];
    op[i] = f2bf(v);
  }
}

__global__ __launch_bounds__(256) void keys_kernel(const float* __restrict__ mem,
                                                   const float* __restrict__ Wmem,
                                                   float* __restrict__ keys)
{
  int stile = blockIdx.x;
  int b = blockIdx.y;
  int t = threadIdx.x;
  __shared__ float Xt[8 * 1032];
  const float* mp = mem + ((size_t)b * SS + (size_t)stile * 8) * DE;
  for (int li = t; li < 8 * 256; li += 256) {
    int row = li >> 8, c4 = li & 255;
    float4 v = *(const float4*)(mp + row * DE + c4 * 4);
    *(float4*)(Xt + row * 1032 + c4 * 4) = v;
  }
  __syncthreads();
  int sl = t >> 5, u = t & 31;
  float acc[4] = {0.f, 0.f, 0.f, 0.f};
  for (int k = 0; k < DE; k++) {
    float x = Xt[sl * 1032 + k];
    const float* wr = Wmem + k * AA;
#pragma unroll
    for (int jj = 0; jj < 4; jj++) acc[jj] += x * wr[u + 32 * jj];
  }
  float* kp = keys + ((size_t)b * SS + (size_t)stile * 8 + sl) * AA;
#pragma unroll
  for (int jj = 0; jj < 4; jj++) kp[u + 32 * jj] = acc[jj];
}

__global__ void mconv_kernel(const float* __restrict__ ck, const float* __restrict__ Wloc,
                             float* __restrict__ M)
{
  int a = threadIdx.x;
  int k = blockIdx.x;
  float acc = 0.f;
  for (int c = 0; c < FF; c++) acc += ck[k * FF + c] * Wloc[c * AA + a];
  M[k * AA + a] = acc;
}

__global__ __launch_bounds__(256) void prenet_all(const int* __restrict__ tokens,
    const float* __restrict__ emb, const float* __restrict__ Wp1, const float* __restrict__ bp1,
    const float* __restrict__ Wp2, const float* __restrict__ bp2, float* __restrict__ P)
{
  int tstep = blockIdx.x;
  int bh = blockIdx.y;
  int t = threadIdx.x;
  __shared__ float X[16 * 512];
  __shared__ float P1[16 * 256];
  for (int li = t; li < 16 * 128; li += 256) {
    int bb = li >> 7, c4 = li & 127;
    int tok = tokens[(bh * 16 + bb) * TT + tstep];
    *(float4*)(X + bb * 512 + c4 * 4) = *(const float4*)(emb + (size_t)tok * EM + c4 * 4);
  }
  __syncthreads();
  int j = t;
  float acc[16];
#pragma unroll
  for (int i = 0; i < 16; i++) acc[i] = 0.f;
  for (int k = 0; k < EM; k++) {
    float w = Wp1[k * PR + j];
#pragma unroll
    for (int i = 0; i < 16; i++) acc[i] += X[i * 512 + k] * w;
  }
#pragma unroll
  for (int i = 0; i < 16; i++) P1[i * 256 + j] = fmaxf(acc[i] + bp1[j], 0.f);
  __syncthreads();
#pragma unroll
  for (int i = 0; i < 16; i++) acc[i] = 0.f;
  for (int k = 0; k < PR; k++) {
    float w = Wp2[k * PR + j];
#pragma unroll
    for (int i = 0; i < 16; i++) acc[i] += P1[i * 256 + k] * w;
  }
  float* outp = P + (size_t)tstep * BB * PR + (size_t)bh * 16 * PR;
#pragma unroll
  for (int i = 0; i < 16; i++) outp[i * PR + j] = fmaxf(acc[i] + bp2[j], 0.f);
}

// ---------------- MFMA bf16 batched GEMM ----------------
__global__ __launch_bounds__(256) void gemm_mfma(
    const float* __restrict__ x0, int len0,
    const float* __restrict__ x1, int len1,
    const float* __restrict__ x2, int len2,
    const ushort* __restrict__ WUP, int nS, int chunk,
    float* __restrict__ zp)
{
  __shared__ alignas(16) ushort wlT[3 * 8192];
  __shared__ alignas(16) ushort xl[32 * 392];
  const int jb = blockIdx.x, kc = blockIdx.y;
  const int t = threadIdx.x;
  const int lane = t & 63;
  const int wv = __builtin_amdgcn_readfirstlane(t >> 6);
  const int PADK = chunk + 8;
  const int nst = chunk >> 6;
  const int k0 = kc * chunk;
  const int S0 = k0 >> 5;
  const size_t jbS = (size_t)jb * nS;
  const int lenW01 = len0 + len1;
  const int ktot = lenW01 + len2;

  auto stage = [&](int s) {
    int buf = s % 3;
    int Sb = S0 + s * 2;
#pragma unroll
    for (int sub = 0; sub < 4; sub++) {
      int inst = wv * 4 + sub;
      const ushort* src = WUP + (jbS + Sb + (inst >> 3)) * 4096
                        + (size_t)(((inst & 7) * 64 + lane) * 8);
      ushort* dst = wlT + buf * 8192 + inst * 512;
      gload16(src, dst);
    }
  };

  stage(0);
  stage(1);

  for (int b = 0; b < 32; b++) {
    for (int kk = t; kk < chunk; kk += 256) {
      int k = k0 + kk;
      float val = 0.f;
      if (k < ktot) {
        const float* xp; int str; int off;
        if (k < len0)        { xp = x0; str = len0; off = k; }
        else if (k < lenW01) { xp = x1; str = len1; off = k - len0; }
        else                 { xp = x2; str = len2; off = k - lenW01; }
        val = xp[(size_t)b * str + off];
      }
      xl[b * PADK + kk] = f2bf(val);
    }
  }
  __syncthreads();

  f32x4 acc[2][2];
#pragma unroll
  for (int mt = 0; mt < 2; mt++)
#pragma unroll
    for (int nt = 0; nt < 2; nt++)
#pragma unroll
      for (int r = 0; r < 4; r++) acc[mt][nt][r] = 0.f;

  const int lane15 = lane & 15, kg = lane >> 4;

  for (int s = 0; s < nst; s++) {
    if (s + 2 < nst) stage(s + 2);
    int ahead = nst - 1 - s; if (ahead > 2) ahead = 2;
    if (ahead == 2)      asm volatile("s_waitcnt vmcnt(8)");
    else if (ahead == 1) asm volatile("s_waitcnt vmcnt(4)");
    else                 asm volatile("s_waitcnt vmcnt(0)");
    __builtin_amdgcn_s_barrier();
    __builtin_amdgcn_sched_barrier(0);
    const ushort* bb = wlT + (s % 3) * 8192 + kg * 1024 + (wv * 32 + lane15) * 8;
    const ushort* ab = xl + lane15 * PADK + s * 64 + kg * 8;
#pragma unroll
    for (int kh = 0; kh < 2; kh++) {
      short8 b0 = *(const short8*)(bb + kh * 4096);
      short8 b1 = *(const short8*)(bb + kh * 4096 + 128);
      short8 a0 = *(const short8*)(ab + kh * 32);
      short8 a1 = *(const short8*)(ab + kh * 32 + 16 * PADK);
      acc[0][0] = __builtin_amdgcn_mfma_f32_16x16x32_bf16(a0, b0, acc[0][0], 0, 0, 0);
      acc[0][1] = __builtin_amdgcn_mfma_f32_16x16x32_bf16(a0, b1, acc[0][1], 0, 0, 0);
      acc[1][0] = __builtin_amdgcn_mfma_f32_16x16x32_bf16(a1, b0, acc[1][0], 0, 0, 0);
      acc[1][1] = __builtin_amdgcn_mfma_f32_16x16x32_bf16(a1, b1, acc[1][1], 0, 0, 0);
    }
    asm volatile("s_waitcnt lgkmcnt(0)");
    __builtin_amdgcn_sched_barrier(0);
    __builtin_amdgcn_s_barrier();
  }

  int colb = jb * 128 + wv * 32 + lane15;
  int rowb = kg * 4;
#pragma unroll
  for (int mt = 0; mt < 2; mt++)
#pragma unroll
    for (int nt = 0; nt < 2; nt++)
#pragma unroll
      for (int r = 0; r < 4; r++) {
        int b = mt * 16 + rowb + r;
        zp[((size_t)kc * BB + b) * 4096 + colb + nt * 16] = acc[mt][nt][r];
      }
}

// ---------------- fp32 deep-pipelined GEMV (cls layer only) ----------------
__global__ __launch_bounds__(256) void gemv_pipe(
    const float* __restrict__ x0, int len0,
    const float* __restrict__ x1, int len1,
    const float* __restrict__ x2, int len2,
    const float* __restrict__ Wmat, const float* __restrict__ Umat,
    int N, int chunk, float* __restrict__ zp)
{
  __shared__ float wl[NBUF * KSTEP * 256];
  __shared__ float xl[32 * 256];
  int jb = blockIdx.x, kc = blockIdx.y;
  int t = threadIdx.x;
  int lane = t & 63;
  int wv = __builtin_amdgcn_readfirstlane(t >> 6);
  int lenW = len0 + len1;
  int k0 = kc * chunk;
  int nst = chunk >> 4;
  int colbase = jb * 256 + lane * 4;
  bool jok = (colbase + 4 <= N);

#pragma unroll
  for (int bi = 0; bi < 8; bi++) {
    int b = wv * 8 + bi;
    for (int kk = lane; kk < chunk; kk += 64) {
      int k = k0 + kk;
      const float* xp; int str; int off;
      if (k < len0)      { xp = x0; str = len0; off = k; }
      else if (k < lenW) { xp = x1; str = len1; off = k - len0; }
      else               { xp = x2; str = len2; off = k - lenW; }
      xl[b * 256 + kk] = xp[(size_t)b * str + off];
    }
  }
  __syncthreads();

  auto stage = [&](int s) {
    int buf = s % NBUF;
    int rbase = k0 + s * KSTEP + wv * 4;
#pragma unroll
    for (int rr = 0; rr < 4; rr++) {
      int r = rbase + rr;
      const float* src = (r < lenW) ? (Wmat + (size_t)r * N + colbase)
                                    : (Umat + (size_t)(r - lenW) * N + colbase);
      float* dst = &wl[(buf * KSTEP + (wv * 4 + rr)) * 256];
      if (jok) gload16(src, dst);
    }
  };

  if (nst > 0) stage(0);
  if (nst > 1) stage(1);

  float acc[8][4];
#pragma unroll
  for (int bi = 0; bi < 8; bi++)
    for (int cc = 0; cc < 4; cc++) acc[bi][cc] = 0.f;

  for (int s = 0; s < nst; s++) {
    if (s + 2 < nst) stage(s + 2);
    int ahead = nst - 1 - s; if (ahead > 2) ahead = 2;
    if (ahead == 2)      asm volatile("s_waitcnt vmcnt(8)");
    else if (ahead == 1) asm volatile("s_waitcnt vmcnt(4)");
    else                 asm volatile("s_waitcnt vmcnt(0)");
    __builtin_amdgcn_s_barrier();
    __builtin_amdgcn_sched_barrier(0);
    const float* wb = &wl[(s % NBUF) * KSTEP * 256];
    int xoff = s * KSTEP;
#pragma unroll
    for (int k4 = 0; k4 < 4; k4++) {
      float4 xv[8];
#pragma unroll
      for (int bi = 0; bi < 8; bi++)
        xv[bi] = *(const float4*)&xl[(wv * 8 + bi) * 256 + xoff + k4 * 4];
#pragma unroll
      for (int kk = 0; kk < 4; kk++) {
        float4 w = *(const float4*)&wb[(k4 * 4 + kk) * 256 + lane * 4];
#pragma unroll
        for (int bi = 0; bi < 8; bi++) {
          float xs = (&xv[bi].x)[kk];
          acc[bi][0] += xs * w.x; acc[bi][1] += xs * w.y;
          acc[bi][2] += xs * w.z; acc[bi][3] += xs * w.w;
        }
      }
    }
    asm volatile("s_waitcnt lgkmcnt(0)");
    __builtin_amdgcn_sched_barrier(0);
    __builtin_amdgcn_s_barrier();
  }

  if (jok) {
#pragma unroll
    for (int bi = 0; bi < 8; bi++) {
      int b = wv * 8 + bi;
      *(float4*)&zp[((size_t)kc * BB + b) * N + colbase] =
          make_float4(acc[bi][0], acc[bi][1], acc[bi][2], acc[bi][3]);
    }
  }
}

// ---------------- per-step small kernels ----------------

__global__ __launch_bounds__(256) void lstm_finish(const float* __restrict__ zpart,
    int nkc, const float* __restrict__ bias, float* __restrict__ h, float* __restrict__ c,
    const float* __restrict__ Wq, float* __restrict__ pqp)
{
  int b = blockIdx.x;
  int q = blockIdx.y;
  int t = threadIdx.x;
  int j = q * 256 + t;
  float zi = bias[j], zf = bias[LU + j], zg = bias[2 * LU + j], zo = bias[3 * LU + j];
  for (int kc = 0; kc < nkc; kc++) {
    const float* zpt = zpart + ((size_t)kc * BB + b) * 4096;
    zi += zpt[j]; zf += zpt[LU + j]; zg += zpt[2 * LU + j]; zo += zpt[3 * LU + j];
  }
  float cn = fsig(zf) * c[b * LU + j] + fsig(zi) * ftanh(zg);
  float hn = fsig(zo) * ftanh(cn);
  c[b * LU + j] = cn;
  h[b * LU + j] = hn;

  if (pqp) {
    __shared__ float sh[256];
    __shared__ float sh2[256];
    sh[t] = hn;
    __syncthreads();
    int a = t & 127, half = t >> 7;
    float acc = 0.f;
    const float* wq = Wq + ((size_t)(q * 256 + half * 128)) * AA + a;
#pragma unroll 4
    for (int jj = 0; jj < 128; jj++) acc += sh[half * 128 + jj] * wq[(size_t)jj * AA];
    sh2[t] = acc;
    __syncthreads();
    if (t < 128) pqp[(size_t)q * BB * AA + b * AA + t] = sh2[t] + sh2[t + 128];
  }
}

// energy v2: thread owns 8 s x 8 a; Ml/astT via ds_read_b128; fast tanh.
__global__ __launch_bounds__(256) void energy_v2(const float* __restrict__ keys,
    const float* __restrict__ pqp, const float* __restrict__ M, const float* __restrict__ ast,
    const float* __restrict__ Wv, const float* __restrict__ bv, const int* __restrict__ mlen,
    float* __restrict__ e)
{
  int tile = blockIdx.x, b = blockIdx.y;
  int s0 = tile * 128;
  int ml = mlen[b];
  if (s0 >= ml) return;
  __shared__ alignas(16) float astT[46 * 8];
  __shared__ alignas(16) float Ml4[31 * 132];
  __shared__ alignas(16) float wvp[256];
  int t = threadIdx.x;
  for (int idx = t; idx < 368; idx += 256) {
    int G = idx >> 3, i = idx & 7;
    int s = s0 + G - 15 + 16 * i;
    astT[idx] = (s >= 0 && s < SS) ? ast[b * SS + s] : 0.f;
  }
  for (int idx = t; idx < KK * AA; idx += 256) {
    int k = idx >> 7, a = idx & 127;
    Ml4[k * 132 + a] = M[idx];
  }
  if (t < 128) wvp[t] = Wv[t];
  else {
    int a = t - 128;
    wvp[128 + a] = pqp[b * AA + a] + pqp[(size_t)BB * AA + b * AA + a]
                 + pqp[(size_t)2 * BB * AA + b * AA + a]
                 + pqp[(size_t)3 * BB * AA + b * AA + a];
  }
  __syncthreads();
  int u = t & 15, g = t >> 4;
  int a0 = u * 8;
  float4 wv0 = *(float4*)&wvp[a0], wv1 = *(float4*)&wvp[a0 + 4];
  float4 pq0 = *(float4*)&wvp[128 + a0], pq1 = *(float4*)&wvp[128 + a0 + 4];
  float arg[8][8];
#pragma unroll
  for (int i = 0; i < 8; i++) {
    int s = s0 + g + 16 * i;
    if (s < SS) {
      const float* kp = keys + ((size_t)b * SS + s) * AA + a0;
      float4 k0 = *(const float4*)kp, k1 = *(const float4*)(kp + 4);
      arg[i][0] = k0.x + pq0.x; arg[i][1] = k0.y + pq0.y;
      arg[i][2] = k0.z + pq0.z; arg[i][3] = k0.w + pq0.w;
      arg[i][4] = k1.x + pq1.x; arg[i][5] = k1.y + pq1.y;
      arg[i][6] = k1.z + pq1.z; arg[i][7] = k1.w + pq1.w;
    } else {
#pragma unroll
      for (int jj = 0; jj < 8; jj++) arg[i][jj] = 0.f;
    }
  }
  for (int k = 0; k < KK; k++) {
    float4 m0 = *(float4*)&Ml4[k * 132 + a0];
    float4 m1 = *(float4*)&Ml4[k * 132 + a0 + 4];
    float4 as0 = *(float4*)&astT[(g + k) * 8];
    float4 as1 = *(float4*)&astT[(g + k) * 8 + 4];
    float asv[8] = {as0.x, as0.y, as0.z, as0.w, as1.x, as1.y, as1.z, as1.w};
#pragma unroll
    for (int i = 0; i < 8; i++) {
      float aw = asv[i];
      arg[i][0] += aw * m0.x; arg[i][1] += aw * m0.y;
      arg[i][2] += aw * m0.z; arg[i][3] += aw * m0.w;
      arg[i][4] += aw * m1.x; arg[i][5] += aw * m1.y;
      arg[i][6] += aw * m1.z; arg[i][7] += aw * m1.w;
    }
  }
  float bvv = bv[0];
#pragma unroll
  for (int i = 0; i < 8; i++) {
    int s = s0 + g + 16 * i;
    float v = ftanh(arg[i][0]) * wv0.x + ftanh(arg[i][1]) * wv0.y
            + ftanh(arg[i][2]) * wv0.z + ftanh(arg[i][3]) * wv0.w
            + ftanh(arg[i][4]) * wv1.x + ftanh(arg[i][5]) * wv1.y
            + ftanh(arg[i][6]) * wv1.z + ftanh(arg[i][7]) * wv1.w;
#pragma unroll
    for (int m = 1; m < 16; m <<= 1) v += __shfl_xor(v, m);
    if (u == 0 && s < SS) e[b * SS + s] = (s < ml) ? (v + bvv) : -1e9f;
  }
}

// softmax (recomputed per block) + ast update + ctx partials (no atomics)
__global__ __launch_bounds__(256) void ctx_sm_part(const float* __restrict__ e,
    const int* __restrict__ mlen, const ushort* __restrict__ mem_bf,
    float* __restrict__ ast, float* __restrict__ cp)
{
  int sc = blockIdx.x, b = blockIdx.y;
  int ml = mlen[b];
  int s0 = sc * 100;
  int cnt = ml - s0; if (cnt > 100) cnt = 100;
  if (cnt <= 0) return;
  int t = threadIdx.x;
  __shared__ float red[4];
  __shared__ float alsh[100];
  const float* er = e + b * SS;
  float m = -3e38f;
  for (int s = t; s < ml; s += 256) m = fmaxf(m, er[s]);
#pragma unroll
  for (int msk = 1; msk < 64; msk <<= 1) m = fmaxf(m, __shfl_xor(m, msk));
  if ((t & 63) == 0) red[t >> 6] = m;
  __syncthreads();
  m = fmaxf(fmaxf(red[0], red[1]), fmaxf(red[2], red[3]));
  __syncthreads();
  float sum = 0.f;
  for (int s = t; s < ml; s += 256) sum += __expf(er[s] - m);
#pragma unroll
  for (int msk = 1; msk < 64; msk <<= 1) sum += __shfl_xor(sum, msk);
  if ((t & 63) == 0) red[t >> 6] = sum;
  __syncthreads();
  float inv = 1.f / (red[0] + red[1] + red[2] + red[3]);
  if (t < cnt) {
    float a_ = __expf(er[s0 + t] - m) * inv;
    alsh[t] = a_;
    ast[b * SS + s0 + t] += a_;
  }
  __syncthreads();
  float4 acc = make_float4(0.f, 0.f, 0.f, 0.f);
  const ushort* mp = mem_bf + ((size_t)b * SS + s0) * DE + t * 4;
#pragma unroll 4
  for (int i = 0; i < cnt; i++) {
    uint2 v = *(const uint2*)(mp + (size_t)i * DE);
    float a_ = alsh[i];
    acc.x += a_ * bf2f((ushort)(v.x & 0xffff));
    acc.y += a_ * bf2f((ushort)(v.x >> 16));
    acc.z += a_ * bf2f((ushort)(v.y & 0xffff));
    acc.w += a_ * bf2f((ushort)(v.y >> 16));
  }
  *(float4*)&cp[((size_t)sc * BB + b) * DE + t * 4] = acc;
}

__global__ __launch_bounds__(256) void ctx_red(const float* __restrict__ cp,
    const int* __restrict__ mlen, float* __restrict__ ctx)
{
  int b = blockIdx.x;
  int t = threadIdx.x;
  int nsc = (mlen[b] + 99) / 100; if (nsc > 16) nsc = 16;
  float4 acc = make_float4(0.f, 0.f, 0.f, 0.f);
  for (int sc = 0; sc < nsc; sc++) {
    float4 v = *(const float4*)&cp[((size_t)sc * BB + b) * DE + t * 4];
    acc.x += v.x; acc.y += v.y; acc.z += v.z; acc.w += v.w;
  }
  *(float4*)&ctx[b * DE + t * 4] = acc;
}

__global__ __launch_bounds__(512) void cls_stp(const float* __restrict__ zp,
    const float* __restrict__ bc, const float* __restrict__ h1,
    const float* __restrict__ Ws, const float* __restrict__ bs,
    float* __restrict__ out, int tstep)
{
  int b = blockIdx.x, t = threadIdx.x;
  float sacc = 0.f;
  for (int k = t; k < LU; k += 512) sacc += h1[b * LU + k] * Ws[k];
  float* orow = out + (size_t)b * TT * VV + (size_t)tstep * VV;
  for (int v = t; v < VV; v += 512) {
    float acc = bc[v];
#pragma unroll
    for (int kc = 0; kc < KSC; kc++) acc += zp[((size_t)kc * BB + b) * VV + v];
    orow[v] = acc;
    sacc += acc * Ws[LU + v];
  }
#pragma unroll
  for (int msk = 1; msk < 64; msk <<= 1) sacc += __shfl_xor(sacc, msk);
  __shared__ float red[8];
  if ((t & 63) == 0) red[t >> 6] = sacc;
  __syncthreads();
  if (t == 0) {
    float s = bs[0];
#pragma unroll
    for (int i = 0; i < 8; i++) s += red[i];
    out[(size_t)BB * TT * VV + (size_t)b * TT + tstep] = s;
  }
}

// ---------------- launcher ----------------

extern "C" void kernel_launch(void* const* d_in, const int* in_sizes, int n_in,
                              void* d_out, int out_size, void* d_ws, size_t ws_size,
                              hipStream_t stream)
{
  const int*   tokens = (const int*)  d_in[0];
  const float* memory = (const float*)d_in[1];
  const int*   mlen   = (const int*)  d_in[2];
  const float* emb    = (const float*)d_in[3];
  const float* Wp1    = (const float*)d_in[4];
  const float* bp1    = (const float*)d_in[5];
  const float* Wp2    = (const float*)d_in[6];
  const float* bp2    = (const float*)d_in[7];
  const float* Wq     = (const float*)d_in[8];
  const float* Wmem   = (const float*)d_in[9];
  const float* convk  = (const float*)d_in[10];
  const float* Wloc   = (const float*)d_in[11];
  const float* Wv     = (const float*)d_in[12];
  const float* bv     = (const float*)d_in[13];
  const float* Wa     = (const float*)d_in[14];
  const float* Ua     = (const float*)d_in[15];
  const float* ba     = (const float*)d_in[16];
  const float* W0     = (const float*)d_in[17];
  const float* U0     = (const float*)d_in[18];
  const float* b0     = (const float*)d_in[19];
  const float* W1     = (const float*)d_in[20];
  const float* U1     = (const float*)d_in[21];
  const float* b1     = (const float*)d_in[22];
  const float* Wc     = (const float*)d_in[23];
  const float* bc     = (const float*)d_in[24];
  const float* Ws     = (const float*)d_in[25];
  const float* bs     = (const float*)d_in[26];
  float* out = (float*)d_out;
  float* ws = (float*)d_ws;

  size_t o = 0;
  float* keys  = ws + o;  o += (size_t)BB * SS * AA;
  float* M     = ws + o;  o += 4096;
  float* P_all = ws + o;  o += (size_t)TT * BB * PR;
  float* st    = ws + o;
  float* h_a = st;
  float* c_a = h_a + BB * LU;
  float* h0  = c_a + BB * LU;
  float* c0  = h0 + BB * LU;
  float* h1  = c0 + BB * LU;
  float* c1  = h1 + BB * LU;
  float* ctx = c1 + BB * LU;
  float* ast = ctx + BB * DE;
  size_t stcount = (size_t)6 * BB * LU + (size_t)BB * DE + (size_t)BB * SS;
  o += stcount;
  float* pqp  = ws + o;  o += (size_t)4 * BB * AA;
  float* ebuf = ws + o;  o += (size_t)BB * SS;
  float* zp   = ws + o;  o += (size_t)8 * BB * 4096;
  float* cp   = ws + o;  o += (size_t)16 * BB * DE;
  ushort* mem_bf = (ushort*)(ws + o);  o += (size_t)BB * SS * DE / 2;
  ushort* WUPa   = (ushort*)(ws + o);  o += (size_t)2560 * 4096 / 2;
  ushort* WUP0   = (ushort*)(ws + o);  o += (size_t)3072 * 4096 / 2;
  ushort* WUP1   = (ushort*)(ws + o);  o += (size_t)2048 * 4096 / 2;

  hipMemsetAsync(st, 0, stcount * sizeof(float), stream);
  conv_mem<<<(BB * SS * DE / 4 + 255) / 256, 256, 0, stream>>>(memory, mem_bf,
                                                               BB * SS * DE / 4);
  pack_wu<<<32 * 80 * 4, 256, 0, stream>>>(Wa, Ua, PR + DE, 2304, WUPa, 80);  // K pad 2560
  pack_wu<<<32 * 96 * 4, 256, 0, stream>>>(W0, U0, LU + DE, 3072, WUP0, 96);  // K=3072
  pack_wu<<<32 * 64 * 4, 256, 0, stream>>>(W1, U1, LU,      2048, WUP1, 64);  // K=2048
  keys_kernel<<<dim3(200, BB), 256, 0, stream>>>(memory, Wmem, keys);
  mconv_kernel<<<KK, AA, 0, stream>>>(convk, Wloc, M);
  prenet_all<<<dim3(TT, 2), 256, 0, stream>>>(tokens, emb, Wp1, bp1, Wp2, bp2, P_all);

  for (int tstep = 0; tstep < TT; tstep++) {
    // attention LSTM: [p,ctx]@Wa + h_a@Ua   Kpad=2560, kc=8, chunk=320 -> grid 256
    gemm_mfma<<<dim3(32, 8), 256, 0, stream>>>(
        P_all + (size_t)tstep * BB * PR, PR, ctx, DE, h_a, LU, WUPa, 80, 320, zp);
    lstm_finish<<<dim3(BB, 4), 256, 0, stream>>>(zp, 8, ba, h_a, c_a, Wq, pqp);
    energy_v2<<<dim3(13, BB), 256, 0, stream>>>(keys, pqp, M, ast, Wv, bv, mlen, ebuf);
    ctx_sm_part<<<dim3(16, BB), 256, 0, stream>>>(ebuf, mlen, mem_bf, ast, cp);
    ctx_red<<<BB, 256, 0, stream>>>(cp, mlen, ctx);
    // LSTM0: [h_a,ctx]@W0 + h0@U0   K=3072, kc=8, chunk=384 -> grid 256
    gemm_mfma<<<dim3(32, 8), 256, 0, stream>>>(
        h_a, LU, ctx, DE, h0, LU, WUP0, 96, 384, zp);
    lstm_finish<<<dim3(BB, 4), 256, 0, stream>>>(zp, 8, b0, h0, c0, Wq, nullptr);
    // LSTM1: h0@W1 + h1@U1   K=2048, kc=8, chunk=256 -> grid 256
    gemm_mfma<<<dim3(32, 8), 256, 0, stream>>>(
        h0, LU, h1, LU, h0, 0, WUP1, 64, 256, zp);
    lstm_finish<<<dim3(BB, 4), 256, 0, stream>>>(zp, 8, b1, h1, c1, Wq, nullptr);
    // cls = [h1,ctx]@Wc + bc (fp32 path for precision)
    gemv_pipe<<<dim3(4, KSC), 256, 0, stream>>>(
        h1, LU, ctx, DE, h1, 0, Wc, Wc, VV, 64, zp);
    cls_stp<<<BB, 512, 0, stream>>>(zp, bc, h1, Ws, bs, out, tstep);
  }
}